// Round 1
// baseline (1738.362 us; speedup 1.0000x reference)
//
#include <hip/hip_runtime.h>

#define NF 128  // feature width for x / hidden layers

// ---------------- CSR build ----------------

__global__ void deg_kernel(const int* __restrict__ dst, int* __restrict__ deg, int E) {
    int e = blockIdx.x * 256 + threadIdx.x;
    if (e < E) atomicAdd(&deg[dst[e]], 1);
}

__global__ void scan_kernel(const int* __restrict__ deg, int* __restrict__ offs,
                            float* __restrict__ rdeg, int N, int E) {
    __shared__ int sb[1024];
    int t = threadIdx.x;
    int chunk = (N + 1023) >> 10;
    int lo = t * chunk;
    int hi = min(lo + chunk, N);
    int sum = 0;
    for (int i = lo; i < hi; ++i) sum += deg[i];
    sb[t] = sum;
    __syncthreads();
    for (int d = 1; d < 1024; d <<= 1) {
        int v = (t >= d) ? sb[t - d] : 0;
        __syncthreads();
        sb[t] += v;
        __syncthreads();
    }
    int run = sb[t] - sum;  // exclusive prefix of this thread's chunk
    for (int i = lo; i < hi; ++i) {
        int dg = deg[i];
        offs[i] = run;
        rdeg[i] = 1.0f / (float)(dg > 1 ? dg : 1);
        run += dg;
    }
    if (t == 1023) offs[N] = run;  // == E
}

__global__ void fill_kernel(const int* __restrict__ src, const int* __restrict__ dst,
                            const int* __restrict__ offs, int* __restrict__ cursor,
                            int* __restrict__ csr, int E) {
    int e = blockIdx.x * 256 + threadIdx.x;
    if (e >= E) return;
    int d = dst[e];
    int pos = atomicAdd(&cursor[d], 1);
    csr[offs[d] + pos] = src[e];
}

// ---------------- mean aggregation (one wave per node) ----------------

__global__ __launch_bounds__(256) void agg_kernel(
        const float* __restrict__ h, const int* __restrict__ offs,
        const int* __restrict__ csr, const float* __restrict__ rdeg,
        float* __restrict__ meanout, int N) {
    int node = blockIdx.x * 4 + (threadIdx.x >> 6);
    int lane = threadIdx.x & 63;
    if (node >= N) return;
    int s0 = offs[node], s1 = offs[node + 1];
    float ax = 0.f, ay = 0.f;
    for (int base = s0; base < s1; base += 64) {
        int cnt = min(64, s1 - base);
        int nid = (lane < cnt) ? csr[base + lane] : 0;
        for (int j = 0; j < cnt; ++j) {
            int s = __shfl(nid, j, 64);
            const float2 v = *(const float2*)&h[(size_t)s * NF + lane * 2];
            ax += v.x;
            ay += v.y;
        }
    }
    float r = rdeg[node];
    float2 o;
    o.x = ax * r;
    o.y = ay * r;
    *(float2*)&meanout[(size_t)node * NF + lane * 2] = o;
}

// ---------------- fused dual linear: out = mean@Wl^T + h@Wr^T + b (opt relu) -----

template <int FOUT, bool RELU>
__global__ __launch_bounds__(256) void linear_kernel(
        const float* __restrict__ mean, const float* __restrict__ hin,
        const float* __restrict__ Wl, const float* __restrict__ Wr,
        const float* __restrict__ bias, float* __restrict__ out, int N) {
    constexpr int FG = FOUT / 4;       // feature groups (each = 4 features)
    constexpr int NPB = 4096 / FOUT;   // nodes per block (128->32, 64->64)
    __shared__ float ms[NPB * NF];
    __shared__ float hs[NPB * NF];

    const int tid = threadIdx.x;
    const int nodeBase = blockIdx.x * NPB;

    // cooperative staging of input tiles (float4-coalesced)
    const int totalV4 = NPB * (NF / 4);
    for (int idx = tid; idx < totalV4; idx += 256) {
        int n = idx >> 5;       // NF/4 == 32 float4 per row
        int k4 = idx & 31;
        int gnode = nodeBase + n;
        float4 mv = make_float4(0.f, 0.f, 0.f, 0.f);
        float4 hv = make_float4(0.f, 0.f, 0.f, 0.f);
        if (gnode < N) {
            mv = *(const float4*)&mean[(size_t)gnode * NF + k4 * 4];
            hv = *(const float4*)&hin[(size_t)gnode * NF + k4 * 4];
        }
        *(float4*)&ms[idx * 4] = mv;
        *(float4*)&hs[idx * 4] = hv;
    }
    __syncthreads();

    const int fg = tid % FG;   // feature group -> features f0..f0+3
    const int ng = tid / FG;   // node group -> nodes ng*4..ng*4+3
    const int f0 = fg * 4;
    const int nb = ng * 4 * NF;

    const float4 bv = *(const float4*)&bias[f0];
    float4 acc0 = bv, acc1 = bv, acc2 = bv, acc3 = bv;

    const float* wlp = Wl + (size_t)f0 * NF;
    const float* wrp = Wr + (size_t)f0 * NF;

#pragma unroll 4
    for (int k4 = 0; k4 < NF / 4; ++k4) {
        const float4 wl0 = *(const float4*)&wlp[0 * NF + k4 * 4];
        const float4 wl1 = *(const float4*)&wlp[1 * NF + k4 * 4];
        const float4 wl2 = *(const float4*)&wlp[2 * NF + k4 * 4];
        const float4 wl3 = *(const float4*)&wlp[3 * NF + k4 * 4];
        const float4 wr0 = *(const float4*)&wrp[0 * NF + k4 * 4];
        const float4 wr1 = *(const float4*)&wrp[1 * NF + k4 * 4];
        const float4 wr2 = *(const float4*)&wrp[2 * NF + k4 * 4];
        const float4 wr3 = *(const float4*)&wrp[3 * NF + k4 * 4];

#define BODY(ACC, NIDX)                                                          \
        {                                                                        \
            float4 m4 = *(const float4*)&ms[nb + NIDX * NF + k4 * 4];            \
            float4 h4 = *(const float4*)&hs[nb + NIDX * NF + k4 * 4];            \
            ACC.x += m4.x * wl0.x + m4.y * wl0.y + m4.z * wl0.z + m4.w * wl0.w   \
                   + h4.x * wr0.x + h4.y * wr0.y + h4.z * wr0.z + h4.w * wr0.w;  \
            ACC.y += m4.x * wl1.x + m4.y * wl1.y + m4.z * wl1.z + m4.w * wl1.w   \
                   + h4.x * wr1.x + h4.y * wr1.y + h4.z * wr1.z + h4.w * wr1.w;  \
            ACC.z += m4.x * wl2.x + m4.y * wl2.y + m4.z * wl2.z + m4.w * wl2.w   \
                   + h4.x * wr2.x + h4.y * wr2.y + h4.z * wr2.z + h4.w * wr2.w;  \
            ACC.w += m4.x * wl3.x + m4.y * wl3.y + m4.z * wl3.z + m4.w * wl3.w   \
                   + h4.x * wr3.x + h4.y * wr3.y + h4.z * wr3.z + h4.w * wr3.w;  \
        }
        BODY(acc0, 0)
        BODY(acc1, 1)
        BODY(acc2, 2)
        BODY(acc3, 3)
#undef BODY
    }

#pragma unroll
    for (int n = 0; n < 4; ++n) {
        int gnode = nodeBase + ng * 4 + n;
        if (gnode >= N) continue;
        float4 o = (n == 0) ? acc0 : (n == 1) ? acc1 : (n == 2) ? acc2 : acc3;
        if (RELU) {
            o.x = fmaxf(o.x, 0.f);
            o.y = fmaxf(o.y, 0.f);
            o.z = fmaxf(o.z, 0.f);
            o.w = fmaxf(o.w, 0.f);
        }
        *(float4*)&out[(size_t)gnode * FOUT + f0] = o;
    }
}

// ---------------- launch ----------------

extern "C" void kernel_launch(void* const* d_in, const int* in_sizes, int n_in,
                              void* d_out, int out_size, void* d_ws, size_t ws_size,
                              hipStream_t stream) {
    const float* x   = (const float*)d_in[0];
    const int*   ei  = (const int*)d_in[1];
    const float* Wl0 = (const float*)d_in[2];
    const float* Wr0 = (const float*)d_in[3];
    const float* b0  = (const float*)d_in[4];
    const float* Wl1 = (const float*)d_in[5];
    const float* Wr1 = (const float*)d_in[6];
    const float* b1  = (const float*)d_in[7];
    const float* Wl2 = (const float*)d_in[8];
    const float* Wr2 = (const float*)d_in[9];
    const float* b2  = (const float*)d_in[10];
    float* out = (float*)d_out;

    const int N = in_sizes[0] / NF;
    const int E = in_sizes[1] / 2;
    const int* srcv = ei;
    const int* dstv = ei + E;

    char* w = (char*)d_ws;
    auto alloc = [&](size_t bytes) {
        void* p = (void*)w;
        w += (bytes + 255) & ~(size_t)255;
        return p;
    };
    float* h1   = (float*)alloc((size_t)N * NF * 4);
    float* h2   = (float*)alloc((size_t)N * NF * 4);
    float* mb   = (float*)alloc((size_t)N * NF * 4);
    int*   deg  = (int*)alloc((size_t)N * 4);
    int*   offs = (int*)alloc((size_t)(N + 1) * 4);
    int*   cur  = (int*)alloc((size_t)N * 4);
    int*   csr  = (int*)alloc((size_t)E * 4);
    float* rdeg = (float*)alloc((size_t)N * 4);

    hipMemsetAsync(deg, 0, (size_t)N * 4, stream);
    hipMemsetAsync(cur, 0, (size_t)N * 4, stream);

    const int eb = (E + 255) / 256;
    deg_kernel<<<eb, 256, 0, stream>>>(dstv, deg, E);
    scan_kernel<<<1, 1024, 0, stream>>>(deg, offs, rdeg, N, E);
    fill_kernel<<<eb, 256, 0, stream>>>(srcv, dstv, offs, cur, csr, E);

    const int ab = (N + 3) / 4;

    // layer 0: x(128) -> h1(128), relu
    agg_kernel<<<ab, 256, 0, stream>>>(x, offs, csr, rdeg, mb, N);
    linear_kernel<128, true><<<(N + 31) / 32, 256, 0, stream>>>(mb, x, Wl0, Wr0, b0, h1, N);

    // layer 1: h1(128) -> h2(128), relu
    agg_kernel<<<ab, 256, 0, stream>>>(h1, offs, csr, rdeg, mb, N);
    linear_kernel<128, true><<<(N + 31) / 32, 256, 0, stream>>>(mb, h1, Wl1, Wr1, b1, h2, N);

    // layer 2: h2(128) -> out(64), no relu
    agg_kernel<<<ab, 256, 0, stream>>>(h2, offs, csr, rdeg, mb, N);
    linear_kernel<64, false><<<(N + 63) / 64, 256, 0, stream>>>(mb, h2, Wl2, Wr2, b2, out, N);
}

// Round 2
// 858.074 us; speedup vs baseline: 2.0259x; 2.0259x over previous
//
#include <hip/hip_runtime.h>

#define NF 128  // feature width for x / hidden layers

typedef __attribute__((ext_vector_type(8))) short bf16x8;
typedef __attribute__((ext_vector_type(4))) float f32x4;

__device__ __forceinline__ unsigned short f2b(float f) {
    unsigned int u = __float_as_uint(f);
    unsigned int r = (u + 0x7fffu + ((u >> 16) & 1u)) >> 16;  // round-nearest-even
    return (unsigned short)r;
}

// ---------------- CSR build ----------------

__global__ void deg_kernel(const int* __restrict__ dst, int* __restrict__ deg, int E) {
    int e = blockIdx.x * 256 + threadIdx.x;
    if (e < E) atomicAdd(&deg[dst[e]], 1);
}

__global__ void scan_kernel(const int* __restrict__ deg, int* __restrict__ offs,
                            float* __restrict__ rdeg, int N, int E) {
    __shared__ int sb[1024];
    int t = threadIdx.x;
    int chunk = (N + 1023) >> 10;
    int lo = t * chunk;
    int hi = min(lo + chunk, N);
    int sum = 0;
    for (int i = lo; i < hi; ++i) sum += deg[i];
    sb[t] = sum;
    __syncthreads();
    for (int d = 1; d < 1024; d <<= 1) {
        int v = (t >= d) ? sb[t - d] : 0;
        __syncthreads();
        sb[t] += v;
        __syncthreads();
    }
    int run = sb[t] - sum;  // exclusive prefix of this thread's chunk
    for (int i = lo; i < hi; ++i) {
        int dg = deg[i];
        offs[i] = run;
        rdeg[i] = 1.0f / (float)(dg > 1 ? dg : 1);
        run += dg;
    }
    if (t == 1023) offs[N] = run;  // == E
}

__global__ void fill_kernel(const int* __restrict__ src, const int* __restrict__ dst,
                            const int* __restrict__ offs, int* __restrict__ cursor,
                            int* __restrict__ csr, int E) {
    int e = blockIdx.x * 256 + threadIdx.x;
    if (e >= E) return;
    int d = dst[e];
    int pos = atomicAdd(&cursor[d], 1);
    csr[offs[d] + pos] = src[e];
}

// ---------------- fp32 -> bf16 conversions ----------------

__global__ void cvt_kernel(const float* __restrict__ x, unsigned short* __restrict__ xb, int n4) {
    int i = blockIdx.x * 256 + threadIdx.x;
    if (i >= n4) return;
    float4 v = *(const float4*)&x[(size_t)i * 4];
    uint2 o;
    o.x = (unsigned int)f2b(v.x) | ((unsigned int)f2b(v.y) << 16);
    o.y = (unsigned int)f2b(v.z) | ((unsigned int)f2b(v.w) << 16);
    *(uint2*)&xb[(size_t)i * 4] = o;
}

// Wcat[f][0:128) = Wl[f][:], Wcat[f][128:256) = Wr[f][:]
__global__ void wcat_kernel(const float* __restrict__ Wl, const float* __restrict__ Wr,
                            unsigned short* __restrict__ Wc, int total /*FOUT*128*/) {
    int i = blockIdx.x * 256 + threadIdx.x;
    if (i >= total) return;
    int f = i >> 7, k = i & 127;
    Wc[f * 256 + k] = f2b(Wl[i]);
    Wc[f * 256 + 128 + k] = f2b(Wr[i]);
}

// ---------------- mean aggregation (bf16 in / bf16 out, one wave per node) ----

__global__ __launch_bounds__(256) void agg_kernel(
        const unsigned short* __restrict__ h, const int* __restrict__ offs,
        const int* __restrict__ csr, const float* __restrict__ rdeg,
        unsigned short* __restrict__ meanout, int N) {
    int node = blockIdx.x * 4 + (threadIdx.x >> 6);
    int lane = threadIdx.x & 63;
    if (node >= N) return;
    int s0 = offs[node], s1 = offs[node + 1];
    float ax = 0.f, ay = 0.f;
    for (int base = s0; base < s1; base += 64) {
        int cnt = min(64, s1 - base);
        int nid = (lane < cnt) ? csr[base + lane] : 0;
        for (int j = 0; j < cnt; ++j) {
            int s = __shfl(nid, j, 64);
            unsigned int v = *(const unsigned int*)&h[(size_t)s * NF + lane * 2];
            ax += __uint_as_float(v << 16);
            ay += __uint_as_float(v & 0xffff0000u);
        }
    }
    float r = rdeg[node];
    unsigned int o = (unsigned int)f2b(ax * r) | ((unsigned int)f2b(ay * r) << 16);
    *(unsigned int*)&meanout[(size_t)node * NF + lane * 2] = o;
}

// ---------------- MFMA GEMM: out = [mean|h] @ Wcat^T + b  (opt relu) ----------
// A tile: 128 nodes x 256 k (bf16, LDS, XOR-swizzled rows)
// W tile: FOUT x 256 k     (bf16, LDS, same swizzle)
// 4 waves: FOUT=128 -> 2x2 wave grid (64x64 each); FOUT=64 -> 4x1 (32x64 each)

template <int FOUT, bool RELU, bool OUTBF>
__global__ __launch_bounds__(256) void gemm_kernel(
        const unsigned short* __restrict__ Abuf,   // mean  [N][128] bf16
        const unsigned short* __restrict__ Hbuf,   // root  [N][128] bf16
        const unsigned short* __restrict__ Wcat,   // [FOUT][256] bf16
        const float* __restrict__ bias,            // [FOUT] fp32
        float* __restrict__ outf, unsigned short* __restrict__ outb,
        int N) {
    __shared__ unsigned short As[128 * 256];
    __shared__ unsigned short Ws[FOUT * 256];

    const int tid = threadIdx.x;
    const int m0 = blockIdx.x * 128;
    char* Ac = (char*)As;
    char* Wc = (char*)Ws;

    // ---- stage A (mean half k<128, root half k>=128), swizzled ----
    for (int idx = tid; idx < 128 * 16; idx += 256) {
        int row = idx >> 4, kc = idx & 15;
        int g = m0 + row;
        uint4 mv = make_uint4(0u, 0u, 0u, 0u);
        uint4 hv = make_uint4(0u, 0u, 0u, 0u);
        if (g < N) {
            mv = *(const uint4*)&Abuf[(size_t)g * NF + kc * 8];
            hv = *(const uint4*)&Hbuf[(size_t)g * NF + kc * 8];
        }
        int sw = (row & 7) << 4;
        *(uint4*)(Ac + row * 512 + ((kc * 16) ^ sw)) = mv;
        *(uint4*)(Ac + row * 512 + ((256 + kc * 16) ^ sw)) = hv;
    }
    // ---- stage W, swizzled ----
    for (int idx = tid; idx < FOUT * 32; idx += 256) {
        int row = idx >> 5, kc = idx & 31;
        uint4 v = *(const uint4*)&Wcat[row * 256 + kc * 8];
        *(uint4*)(Wc + row * 512 + ((kc * 16) ^ ((row & 7) << 4))) = v;
    }
    __syncthreads();

    constexpr int MI = (FOUT == 128) ? 4 : 2;
    constexpr int NI = 4;
    const int wid = tid >> 6, lane = tid & 63;
    const int lm = lane & 15, ko = lane >> 4;
    const int wmBase = (FOUT == 128) ? (wid >> 1) * 64 : wid * 32;
    const int wnBase = (FOUT == 128) ? (wid & 1) * 64 : 0;

    f32x4 acc[MI][NI];
#pragma unroll
    for (int i = 0; i < MI; ++i)
#pragma unroll
        for (int j = 0; j < NI; ++j)
            acc[i][j] = (f32x4){0.f, 0.f, 0.f, 0.f};

#pragma unroll
    for (int ks = 0; ks < 8; ++ks) {
        const int kb = ks * 64 + ko * 16;  // byte offset within a 512B row
        bf16x8 a[MI], b[NI];
#pragma unroll
        for (int i = 0; i < MI; ++i) {
            int row = wmBase + i * 16 + lm;
            a[i] = *(const bf16x8*)(Ac + row * 512 + (kb ^ ((row & 7) << 4)));
        }
#pragma unroll
        for (int j = 0; j < NI; ++j) {
            int row = wnBase + j * 16 + lm;
            b[j] = *(const bf16x8*)(Wc + row * 512 + (kb ^ ((row & 7) << 4)));
        }
#pragma unroll
        for (int i = 0; i < MI; ++i)
#pragma unroll
            for (int j = 0; j < NI; ++j)
                acc[i][j] = __builtin_amdgcn_mfma_f32_16x16x32_bf16(a[i], b[j], acc[i][j], 0, 0, 0);
    }

    // ---- epilogue: bias (+relu), write bf16 or fp32 ----
#pragma unroll
    for (int i = 0; i < MI; ++i) {
        const int rbase = m0 + wmBase + i * 16 + ko * 4;
#pragma unroll
        for (int j = 0; j < NI; ++j) {
            const int col = wnBase + j * 16 + lm;
            const float bv = bias[col];
#pragma unroll
            for (int r = 0; r < 4; ++r) {
                int g = rbase + r;
                if (g >= N) continue;
                float v = acc[i][j][r] + bv;
                if (RELU) v = fmaxf(v, 0.f);
                if (OUTBF) outb[(size_t)g * FOUT + col] = f2b(v);
                else       outf[(size_t)g * FOUT + col] = v;
            }
        }
    }
}

// ---------------- launch ----------------

extern "C" void kernel_launch(void* const* d_in, const int* in_sizes, int n_in,
                              void* d_out, int out_size, void* d_ws, size_t ws_size,
                              hipStream_t stream) {
    const float* x   = (const float*)d_in[0];
    const int*   ei  = (const int*)d_in[1];
    const float* Wl0 = (const float*)d_in[2];
    const float* Wr0 = (const float*)d_in[3];
    const float* b0  = (const float*)d_in[4];
    const float* Wl1 = (const float*)d_in[5];
    const float* Wr1 = (const float*)d_in[6];
    const float* b1  = (const float*)d_in[7];
    const float* Wl2 = (const float*)d_in[8];
    const float* Wr2 = (const float*)d_in[9];
    const float* b2  = (const float*)d_in[10];
    float* out = (float*)d_out;

    const int N = in_sizes[0] / NF;
    const int E = in_sizes[1] / 2;
    const int* srcv = ei;
    const int* dstv = ei + E;

    char* w = (char*)d_ws;
    auto alloc = [&](size_t bytes) {
        void* p = (void*)w;
        w += (bytes + 255) & ~(size_t)255;
        return p;
    };
    unsigned short* xb  = (unsigned short*)alloc((size_t)N * NF * 2);
    unsigned short* h1b = (unsigned short*)alloc((size_t)N * NF * 2);
    unsigned short* h2b = (unsigned short*)alloc((size_t)N * NF * 2);
    unsigned short* mb  = (unsigned short*)alloc((size_t)N * NF * 2);
    unsigned short* Wc0 = (unsigned short*)alloc((size_t)128 * 256 * 2);
    unsigned short* Wc1 = (unsigned short*)alloc((size_t)128 * 256 * 2);
    unsigned short* Wc2 = (unsigned short*)alloc((size_t)64 * 256 * 2);
    int*   deg  = (int*)alloc((size_t)N * 4);
    int*   offs = (int*)alloc((size_t)(N + 1) * 4);
    int*   cur  = (int*)alloc((size_t)N * 4);
    int*   csr  = (int*)alloc((size_t)E * 4);
    float* rdeg = (float*)alloc((size_t)N * 4);

    hipMemsetAsync(deg, 0, (size_t)N * 4, stream);
    hipMemsetAsync(cur, 0, (size_t)N * 4, stream);

    // conversions
    const int n4 = N * NF / 4;
    cvt_kernel<<<(n4 + 255) / 256, 256, 0, stream>>>(x, xb, n4);
    wcat_kernel<<<(128 * 128 + 255) / 256, 256, 0, stream>>>(Wl0, Wr0, Wc0, 128 * 128);
    wcat_kernel<<<(128 * 128 + 255) / 256, 256, 0, stream>>>(Wl1, Wr1, Wc1, 128 * 128);
    wcat_kernel<<<(64 * 128 + 255) / 256, 256, 0, stream>>>(Wl2, Wr2, Wc2, 64 * 128);

    // CSR
    const int eb = (E + 255) / 256;
    deg_kernel<<<eb, 256, 0, stream>>>(dstv, deg, E);
    scan_kernel<<<1, 1024, 0, stream>>>(deg, offs, rdeg, N, E);
    fill_kernel<<<eb, 256, 0, stream>>>(srcv, dstv, offs, cur, csr, E);

    const int ab = (N + 3) / 4;
    const int gb = (N + 127) / 128;

    // layer 0: x(128) -> h1(128), relu
    agg_kernel<<<ab, 256, 0, stream>>>(xb, offs, csr, rdeg, mb, N);
    gemm_kernel<128, true, true><<<gb, 256, 0, stream>>>(mb, xb, Wc0, b0, nullptr, h1b, N);

    // layer 1: h1(128) -> h2(128), relu
    agg_kernel<<<ab, 256, 0, stream>>>(h1b, offs, csr, rdeg, mb, N);
    gemm_kernel<128, true, true><<<gb, 256, 0, stream>>>(mb, h1b, Wc1, b1, nullptr, h2b, N);

    // layer 2: h2(128) -> out(64), no relu
    agg_kernel<<<ab, 256, 0, stream>>>(h2b, offs, csr, rdeg, mb, N);
    gemm_kernel<64, false, false><<<gb, 256, 0, stream>>>(mb, h2b, Wc2, b2, out, nullptr, N);
}

// Round 3
// 657.361 us; speedup vs baseline: 2.6445x; 1.3053x over previous
//
#include <hip/hip_runtime.h>

#define NF 128  // feature width for x / hidden layers

typedef __attribute__((ext_vector_type(8))) short bf16x8;
typedef __attribute__((ext_vector_type(4))) float f32x4;

__device__ __forceinline__ unsigned short f2b(float f) {
    unsigned int u = __float_as_uint(f);
    unsigned int r = (u + 0x7fffu + ((u >> 16) & 1u)) >> 16;  // round-nearest-even
    return (unsigned short)r;
}

// ---------------- CSR build ----------------

__global__ void deg_kernel(const int* __restrict__ dst, int* __restrict__ deg, int E) {
    int e = blockIdx.x * 256 + threadIdx.x;
    if (e < E) atomicAdd(&deg[dst[e]], 1);
}

// phase A: per-block sums of deg
__global__ __launch_bounds__(256) void bsum_kernel(const int* __restrict__ deg,
                                                   int* __restrict__ bsum, int N) {
    int i = blockIdx.x * 256 + threadIdx.x;
    int v = (i < N) ? deg[i] : 0;
#pragma unroll
    for (int d = 32; d; d >>= 1) v += __shfl_down(v, d, 64);
    __shared__ int wsum[4];
    if ((threadIdx.x & 63) == 0) wsum[threadIdx.x >> 6] = v;
    __syncthreads();
    if (threadIdx.x == 0) bsum[blockIdx.x] = wsum[0] + wsum[1] + wsum[2] + wsum[3];
}

// phase B: exclusive scan of block sums (NB <= 512), single block
__global__ __launch_bounds__(512) void bscan_kernel(const int* __restrict__ bsum,
                                                    int* __restrict__ bpre, int NB) {
    __shared__ int s[512];
    int t = threadIdx.x;
    int v = (t < NB) ? bsum[t] : 0;
    s[t] = v;
    __syncthreads();
    for (int d = 1; d < 512; d <<= 1) {
        int u = (t >= d) ? s[t - d] : 0;
        __syncthreads();
        s[t] += u;
        __syncthreads();
    }
    if (t < NB) bpre[t] = s[t] - v;  // exclusive prefix
}

// phase C: offs[i] = bpre[block] + intra-block exclusive scan; rdeg; offs[N]
__global__ __launch_bounds__(256) void offs_kernel(const int* __restrict__ deg,
                                                   const int* __restrict__ bpre,
                                                   int* __restrict__ offs,
                                                   float* __restrict__ rdeg, int N) {
    __shared__ int s[256];
    int i = blockIdx.x * 256 + threadIdx.x;
    int t = threadIdx.x;
    int v = (i < N) ? deg[i] : 0;
    s[t] = v;
    __syncthreads();
    for (int d = 1; d < 256; d <<= 1) {
        int u = (t >= d) ? s[t - d] : 0;
        __syncthreads();
        s[t] += u;
        __syncthreads();
    }
    if (i < N) {
        int excl = bpre[blockIdx.x] + s[t] - v;
        offs[i] = excl;
        rdeg[i] = 1.0f / (float)(v > 1 ? v : 1);
        if (i == N - 1) offs[N] = excl + v;
    }
}

__global__ void fill_kernel(const int* __restrict__ src, const int* __restrict__ dst,
                            const int* __restrict__ offs, int* __restrict__ cursor,
                            int* __restrict__ csr, int E) {
    int e = blockIdx.x * 256 + threadIdx.x;
    if (e >= E) return;
    int d = dst[e];
    int pos = atomicAdd(&cursor[d], 1);
    csr[offs[d] + pos] = src[e];
}

// ---------------- fp32 -> bf16 conversions ----------------

__global__ void cvt_kernel(const float* __restrict__ x, unsigned short* __restrict__ xb, int n4) {
    int i = blockIdx.x * 256 + threadIdx.x;
    if (i >= n4) return;
    float4 v = *(const float4*)&x[(size_t)i * 4];
    uint2 o;
    o.x = (unsigned int)f2b(v.x) | ((unsigned int)f2b(v.y) << 16);
    o.y = (unsigned int)f2b(v.z) | ((unsigned int)f2b(v.w) << 16);
    *(uint2*)&xb[(size_t)i * 4] = o;
}

// Wcat[f][0:128) = Wl[f][:], Wcat[f][128:256) = Wr[f][:]
__global__ void wcat_kernel(const float* __restrict__ Wl, const float* __restrict__ Wr,
                            unsigned short* __restrict__ Wc, int total /*FOUT*128*/) {
    int i = blockIdx.x * 256 + threadIdx.x;
    if (i >= total) return;
    int f = i >> 7, k = i & 127;
    Wc[f * 256 + k] = f2b(Wl[i]);
    Wc[f * 256 + 128 + k] = f2b(Wr[i]);
}

// ---------------- mean aggregation (bf16 in / bf16 out, one wave per node) ----

__global__ __launch_bounds__(256) void agg_kernel(
        const unsigned short* __restrict__ h, const int* __restrict__ offs,
        const int* __restrict__ csr, const float* __restrict__ rdeg,
        unsigned short* __restrict__ meanout, int N) {
    int node = blockIdx.x * 4 + (threadIdx.x >> 6);
    int lane = threadIdx.x & 63;
    if (node >= N) return;
    int s0 = offs[node], s1 = offs[node + 1];
    float ax = 0.f, ay = 0.f;
    for (int base = s0; base < s1; base += 64) {
        int cnt = min(64, s1 - base);
        int nid = (lane < cnt) ? csr[base + lane] : 0;
        for (int j = 0; j < cnt; ++j) {
            int s = __shfl(nid, j, 64);
            unsigned int v = *(const unsigned int*)&h[(size_t)s * NF + lane * 2];
            ax += __uint_as_float(v << 16);
            ay += __uint_as_float(v & 0xffff0000u);
        }
    }
    float r = rdeg[node];
    unsigned int o = (unsigned int)f2b(ax * r) | ((unsigned int)f2b(ay * r) << 16);
    *(unsigned int*)&meanout[(size_t)node * NF + lane * 2] = o;
}

// ---------------- MFMA GEMM: out = [mean|h] @ Wcat^T + b  (opt relu) ----------

template <int FOUT, bool RELU, bool OUTBF>
__global__ __launch_bounds__(256) void gemm_kernel(
        const unsigned short* __restrict__ Abuf,   // mean  [N][128] bf16
        const unsigned short* __restrict__ Hbuf,   // root  [N][128] bf16
        const unsigned short* __restrict__ Wcat,   // [FOUT][256] bf16
        const float* __restrict__ bias,            // [FOUT] fp32
        float* __restrict__ outf, unsigned short* __restrict__ outb,
        int N) {
    __shared__ unsigned short As[128 * 256];
    __shared__ unsigned short Ws[FOUT * 256];

    const int tid = threadIdx.x;
    const int m0 = blockIdx.x * 128;
    char* Ac = (char*)As;
    char* Wc = (char*)Ws;

    // ---- stage A (mean half k<128, root half k>=128), swizzled ----
    for (int idx = tid; idx < 128 * 16; idx += 256) {
        int row = idx >> 4, kc = idx & 15;
        int g = m0 + row;
        uint4 mv = make_uint4(0u, 0u, 0u, 0u);
        uint4 hv = make_uint4(0u, 0u, 0u, 0u);
        if (g < N) {
            mv = *(const uint4*)&Abuf[(size_t)g * NF + kc * 8];
            hv = *(const uint4*)&Hbuf[(size_t)g * NF + kc * 8];
        }
        int sw = (row & 7) << 4;
        *(uint4*)(Ac + row * 512 + ((kc * 16) ^ sw)) = mv;
        *(uint4*)(Ac + row * 512 + ((256 + kc * 16) ^ sw)) = hv;
    }
    // ---- stage W, swizzled ----
    for (int idx = tid; idx < FOUT * 32; idx += 256) {
        int row = idx >> 5, kc = idx & 31;
        uint4 v = *(const uint4*)&Wcat[row * 256 + kc * 8];
        *(uint4*)(Wc + row * 512 + ((kc * 16) ^ ((row & 7) << 4))) = v;
    }
    __syncthreads();

    constexpr int MI = (FOUT == 128) ? 4 : 2;
    constexpr int NI = 4;
    const int wid = tid >> 6, lane = tid & 63;
    const int lm = lane & 15, ko = lane >> 4;
    const int wmBase = (FOUT == 128) ? (wid >> 1) * 64 : wid * 32;
    const int wnBase = (FOUT == 128) ? (wid & 1) * 64 : 0;

    f32x4 acc[MI][NI];
#pragma unroll
    for (int i = 0; i < MI; ++i)
#pragma unroll
        for (int j = 0; j < NI; ++j)
            acc[i][j] = (f32x4){0.f, 0.f, 0.f, 0.f};

#pragma unroll
    for (int ks = 0; ks < 8; ++ks) {
        const int kb = ks * 64 + ko * 16;  // byte offset within a 512B row
        bf16x8 a[MI], b[NI];
#pragma unroll
        for (int i = 0; i < MI; ++i) {
            int row = wmBase + i * 16 + lm;
            a[i] = *(const bf16x8*)(Ac + row * 512 + (kb ^ ((row & 7) << 4)));
        }
#pragma unroll
        for (int j = 0; j < NI; ++j) {
            int row = wnBase + j * 16 + lm;
            b[j] = *(const bf16x8*)(Wc + row * 512 + (kb ^ ((row & 7) << 4)));
        }
#pragma unroll
        for (int i = 0; i < MI; ++i)
#pragma unroll
            for (int j = 0; j < NI; ++j)
                acc[i][j] = __builtin_amdgcn_mfma_f32_16x16x32_bf16(a[i], b[j], acc[i][j], 0, 0, 0);
    }

    // ---- epilogue: bias (+relu), write bf16 or fp32 ----
#pragma unroll
    for (int i = 0; i < MI; ++i) {
        const int rbase = m0 + wmBase + i * 16 + ko * 4;
#pragma unroll
        for (int j = 0; j < NI; ++j) {
            const int col = wnBase + j * 16 + lm;
            const float bv = bias[col];
#pragma unroll
            for (int r = 0; r < 4; ++r) {
                int g = rbase + r;
                if (g >= N) continue;
                float v = acc[i][j][r] + bv;
                if (RELU) v = fmaxf(v, 0.f);
                if (OUTBF) outb[(size_t)g * FOUT + col] = f2b(v);
                else       outf[(size_t)g * FOUT + col] = v;
            }
        }
    }
}

// ---------------- launch ----------------

extern "C" void kernel_launch(void* const* d_in, const int* in_sizes, int n_in,
                              void* d_out, int out_size, void* d_ws, size_t ws_size,
                              hipStream_t stream) {
    const float* x   = (const float*)d_in[0];
    const int*   ei  = (const int*)d_in[1];
    const float* Wl0 = (const float*)d_in[2];
    const float* Wr0 = (const float*)d_in[3];
    const float* b0  = (const float*)d_in[4];
    const float* Wl1 = (const float*)d_in[5];
    const float* Wr1 = (const float*)d_in[6];
    const float* b1  = (const float*)d_in[7];
    const float* Wl2 = (const float*)d_in[8];
    const float* Wr2 = (const float*)d_in[9];
    const float* b2  = (const float*)d_in[10];
    float* out = (float*)d_out;

    const int N = in_sizes[0] / NF;
    const int E = in_sizes[1] / 2;
    const int* srcv = ei;
    const int* dstv = ei + E;

    char* w = (char*)d_ws;
    auto alloc = [&](size_t bytes) {
        void* p = (void*)w;
        w += (bytes + 255) & ~(size_t)255;
        return p;
    };
    unsigned short* xb  = (unsigned short*)alloc((size_t)N * NF * 2);
    unsigned short* h1b = (unsigned short*)alloc((size_t)N * NF * 2);
    unsigned short* h2b = (unsigned short*)alloc((size_t)N * NF * 2);
    unsigned short* mb  = (unsigned short*)alloc((size_t)N * NF * 2);
    unsigned short* Wc0 = (unsigned short*)alloc((size_t)128 * 256 * 2);
    unsigned short* Wc1 = (unsigned short*)alloc((size_t)128 * 256 * 2);
    unsigned short* Wc2 = (unsigned short*)alloc((size_t)64 * 256 * 2);
    int*   deg  = (int*)alloc((size_t)N * 4);
    int*   offs = (int*)alloc((size_t)(N + 1) * 4);
    int*   cur  = (int*)alloc((size_t)N * 4);
    int*   csr  = (int*)alloc((size_t)E * 4);
    float* rdeg = (float*)alloc((size_t)N * 4);
    int*   bsum = (int*)alloc((size_t)1024 * 4);
    int*   bpre = (int*)alloc((size_t)1024 * 4);

    hipMemsetAsync(deg, 0, (size_t)N * 4, stream);
    hipMemsetAsync(cur, 0, (size_t)N * 4, stream);

    // conversions
    const int n4 = N * NF / 4;
    cvt_kernel<<<(n4 + 255) / 256, 256, 0, stream>>>(x, xb, n4);
    wcat_kernel<<<(128 * 128 + 255) / 256, 256, 0, stream>>>(Wl0, Wr0, Wc0, 128 * 128);
    wcat_kernel<<<(128 * 128 + 255) / 256, 256, 0, stream>>>(Wl1, Wr1, Wc1, 128 * 128);
    wcat_kernel<<<(64 * 128 + 255) / 256, 256, 0, stream>>>(Wl2, Wr2, Wc2, 64 * 128);

    // CSR (3-phase parallel scan)
    const int eb = (E + 255) / 256;
    const int nb = (N + 255) / 256;  // 391 blocks <= 512
    deg_kernel<<<eb, 256, 0, stream>>>(dstv, deg, E);
    bsum_kernel<<<nb, 256, 0, stream>>>(deg, bsum, N);
    bscan_kernel<<<1, 512, 0, stream>>>(bsum, bpre, nb);
    offs_kernel<<<nb, 256, 0, stream>>>(deg, bpre, offs, rdeg, N);
    fill_kernel<<<eb, 256, 0, stream>>>(srcv, dstv, offs, cur, csr, E);

    const int ab = (N + 3) / 4;
    const int gb = (N + 127) / 128;

    // layer 0: x(128) -> h1(128), relu
    agg_kernel<<<ab, 256, 0, stream>>>(xb, offs, csr, rdeg, mb, N);
    gemm_kernel<128, true, true><<<gb, 256, 0, stream>>>(mb, xb, Wc0, b0, nullptr, h1b, N);

    // layer 1: h1(128) -> h2(128), relu
    agg_kernel<<<ab, 256, 0, stream>>>(h1b, offs, csr, rdeg, mb, N);
    gemm_kernel<128, true, true><<<gb, 256, 0, stream>>>(mb, h1b, Wc1, b1, nullptr, h2b, N);

    // layer 2: h2(128) -> out(64), no relu
    agg_kernel<<<ab, 256, 0, stream>>>(h2b, offs, csr, rdeg, mb, N);
    gemm_kernel<64, false, false><<<gb, 256, 0, stream>>>(mb, h2b, Wc2, b2, out, nullptr, N);
}

// Round 4
// 465.249 us; speedup vs baseline: 3.7364x; 1.4129x over previous
//
#include <hip/hip_runtime.h>

#define NF 128      // feature width for x / hidden layers
#define CHUNK 4096  // edges per block in CSR-build phase 1

typedef __attribute__((ext_vector_type(8))) short bf16x8;
typedef __attribute__((ext_vector_type(4))) float f32x4;

__device__ __forceinline__ unsigned short f2b(float f) {
    unsigned int u = __float_as_uint(f);
    unsigned int r = (u + 0x7fffu + ((u >> 16) & 1u)) >> 16;  // round-nearest-even
    return (unsigned short)r;
}

// ================= CSR build: bucketed two-phase counting sort =================
// Buckets = 256 consecutive dst nodes. NB = ceil(N/256) (<=512), NBLK = ceil(E/CHUNK) (<=512).

// P1a: per-(block,bucket) histogram, written block-major (coalesced)
__global__ __launch_bounds__(256) void hist_kernel(const int* __restrict__ dst,
                                                   int* __restrict__ hist,
                                                   int E, int NB) {
    __shared__ int h[512];
    const int blk = blockIdx.x;
    for (int i = threadIdx.x; i < NB; i += 256) h[i] = 0;
    __syncthreads();
    const int e0 = blk * CHUNK;
    for (int i = threadIdx.x; i < CHUNK; i += 256) {
        int e = e0 + i;
        if (e < E) atomicAdd(&h[dst[e] >> 8], 1);
    }
    __syncthreads();
    for (int i = threadIdx.x; i < NB; i += 256) hist[blk * NB + i] = h[i];
}

// scan of hist in bucket-major order p = b*NBLK + blk  ->  val(p) = hist[blk*NB + b]
__global__ __launch_bounds__(256) void sb_sum(const int* __restrict__ hist,
                                              int* __restrict__ bsum,
                                              int T, int NB, int NBLK) {
    int i = blockIdx.x * 256 + threadIdx.x;
    int v = 0;
    if (i < T) {
        int b = i / NBLK, blk = i - b * NBLK;
        v = hist[blk * NB + b];
    }
#pragma unroll
    for (int d = 32; d; d >>= 1) v += __shfl_down(v, d, 64);
    __shared__ int wsum[4];
    if ((threadIdx.x & 63) == 0) wsum[threadIdx.x >> 6] = v;
    __syncthreads();
    if (threadIdx.x == 0) bsum[blockIdx.x] = wsum[0] + wsum[1] + wsum[2] + wsum[3];
}

__global__ __launch_bounds__(1024) void sb_scan(const int* __restrict__ bsum,
                                                int* __restrict__ bpre, int NS) {
    __shared__ int s[1024];
    int t = threadIdx.x;
    int v = (t < NS) ? bsum[t] : 0;
    s[t] = v;
    __syncthreads();
    for (int d = 1; d < 1024; d <<= 1) {
        int u = (t >= d) ? s[t - d] : 0;
        __syncthreads();
        s[t] += u;
        __syncthreads();
    }
    if (t < NS) bpre[t] = s[t] - v;
}

__global__ __launch_bounds__(256) void sb_apply(const int* __restrict__ hist,
                                                const int* __restrict__ bpre,
                                                int* __restrict__ base,
                                                int T, int NB, int NBLK) {
    __shared__ int s[256];
    int i = blockIdx.x * 256 + threadIdx.x;
    int t = threadIdx.x;
    int v = 0;
    if (i < T) {
        int b = i / NBLK, blk = i - b * NBLK;
        v = hist[blk * NB + b];
    }
    s[t] = v;
    __syncthreads();
    for (int d = 1; d < 256; d <<= 1) {
        int u = (t >= d) ? s[t - d] : 0;
        __syncthreads();
        s[t] += u;
        __syncthreads();
    }
    if (i < T) base[i] = bpre[blockIdx.x] + s[t] - v;
}

// bstart[b] = base[b*NBLK], bstart[NB] = E
__global__ __launch_bounds__(512) void bstart_kernel(const int* __restrict__ base,
                                                     int* __restrict__ bstart,
                                                     int NB, int NBLK, int E) {
    int i = threadIdx.x;
    if (i < NB) bstart[i] = base[i * NBLK];
    if (i == NB) bstart[i] = E;
}

// P1b: scatter packed records (src | dstLocal<<24) into per-(bucket,block) segments
__global__ __launch_bounds__(256) void scat_kernel(const int* __restrict__ src,
                                                   const int* __restrict__ dst,
                                                   const int* __restrict__ base,
                                                   unsigned int* __restrict__ recs,
                                                   int E, int NB, int NBLK) {
    __shared__ int cur[512];
    const int blk = blockIdx.x;
    for (int b = threadIdx.x; b < NB; b += 256) cur[b] = base[b * NBLK + blk];
    __syncthreads();
    const int e0 = blk * CHUNK;
    for (int i = threadIdx.x; i < CHUNK; i += 256) {
        int e = e0 + i;
        if (e >= E) continue;
        int d = dst[e];
        int b = d >> 8;
        int pos = atomicAdd(&cur[b], 1);
        recs[pos] = (unsigned int)src[e] | ((unsigned int)(d & 255) << 24);
    }
}

// P2: per-bucket local counting sort -> csr + offs + rdeg
__global__ __launch_bounds__(256) void csr_kernel(const unsigned int* __restrict__ recs,
                                                  const int* __restrict__ bstart,
                                                  int* __restrict__ offs,
                                                  float* __restrict__ rdeg,
                                                  int* __restrict__ csr,
                                                  int N, int E) {
    __shared__ int cnt[256];
    __shared__ int sc[256];
    __shared__ int cur[256];
    const int b = blockIdx.x;
    const int t = threadIdx.x;
    const int s0 = bstart[b], s1 = bstart[b + 1];
    cnt[t] = 0;
    __syncthreads();
    for (int i = s0 + t; i < s1; i += 256) atomicAdd(&cnt[recs[i] >> 24], 1);
    __syncthreads();
    int v = cnt[t];
    sc[t] = v;
    __syncthreads();
    for (int d = 1; d < 256; d <<= 1) {
        int u = (t >= d) ? sc[t - d] : 0;
        __syncthreads();
        sc[t] += u;
        __syncthreads();
    }
    int excl = sc[t] - v;
    int node = b * 256 + t;
    if (node < N) {
        offs[node] = s0 + excl;
        rdeg[node] = 1.0f / (float)(v > 1 ? v : 1);
        if (node == N - 1) offs[N] = E;
    }
    cur[t] = s0 + excl;
    __syncthreads();
    for (int i = s0 + t; i < s1; i += 256) {
        unsigned int r = recs[i];
        int pos = atomicAdd(&cur[r >> 24], 1);
        csr[pos] = (int)(r & 0xFFFFFFu);
    }
}

// ---------------- fp32 -> bf16 conversions ----------------

__global__ void cvt_kernel(const float* __restrict__ x, unsigned short* __restrict__ xb, int n4) {
    int i = blockIdx.x * 256 + threadIdx.x;
    if (i >= n4) return;
    float4 v = *(const float4*)&x[(size_t)i * 4];
    uint2 o;
    o.x = (unsigned int)f2b(v.x) | ((unsigned int)f2b(v.y) << 16);
    o.y = (unsigned int)f2b(v.z) | ((unsigned int)f2b(v.w) << 16);
    *(uint2*)&xb[(size_t)i * 4] = o;
}

// Wcat[f][0:128) = Wl[f][:], Wcat[f][128:256) = Wr[f][:]   (k-concat, layers 0/1)
__global__ void wcat_kernel(const float* __restrict__ Wl, const float* __restrict__ Wr,
                            unsigned short* __restrict__ Wc, int total /*128*128*/) {
    int i = blockIdx.x * 256 + threadIdx.x;
    if (i >= total) return;
    int f = i >> 7, k = i & 127;
    Wc[f * 256 + k] = f2b(Wl[i]);
    Wc[f * 256 + 128 + k] = f2b(Wr[i]);
}

// Wst rows 0..63 = Wl2, rows 64..127 = Wr2; bst = [0(64) | b2(64)]  (layer 2 stack)
__global__ void wstack_kernel(const float* __restrict__ Wl, const float* __restrict__ Wr,
                              const float* __restrict__ b2,
                              unsigned short* __restrict__ Wst, float* __restrict__ bst,
                              int total /*64*128*/) {
    int i = blockIdx.x * 256 + threadIdx.x;
    if (i >= total) return;
    int f = i >> 7, k = i & 127;
    Wst[f * 128 + k] = f2b(Wl[i]);
    Wst[(f + 64) * 128 + k] = f2b(Wr[i]);
    if (k == 0) {
        bst[f] = 0.f;
        bst[f + 64] = b2[f];
    }
}

// ---------------- mean aggregation (bf16 in / bf16 out, one wave per node) ----

__global__ __launch_bounds__(256) void agg_kernel(
        const unsigned short* __restrict__ h, const int* __restrict__ offs,
        const int* __restrict__ csr, const float* __restrict__ rdeg,
        unsigned short* __restrict__ meanout, int N) {
    int node = blockIdx.x * 4 + (threadIdx.x >> 6);
    int lane = threadIdx.x & 63;
    if (node >= N) return;
    int s0 = offs[node], s1 = offs[node + 1];
    float ax = 0.f, ay = 0.f;
    for (int base = s0; base < s1; base += 64) {
        int cnt = min(64, s1 - base);
        int nid = (lane < cnt) ? csr[base + lane] : 0;
        for (int j = 0; j < cnt; ++j) {
            int s = __shfl(nid, j, 64);
            unsigned int v = *(const unsigned int*)&h[(size_t)s * NF + lane * 2];
            ax += __uint_as_float(v << 16);
            ay += __uint_as_float(v & 0xffff0000u);
        }
    }
    float r = rdeg[node];
    unsigned int o = (unsigned int)f2b(ax * r) | ((unsigned int)f2b(ay * r) << 16);
    *(unsigned int*)&meanout[(size_t)node * NF + lane * 2] = o;
}

// ---- layer-2 final aggregation: out[i] = mean_j zl[j] + zr[i]  (fp32 out, 64-wide)
// z layout: [N][128] bf16, zl = cols 0..63, zr = cols 64..127. Two nodes per wave.

__global__ __launch_bounds__(256) void agg2_kernel(
        const unsigned short* __restrict__ z, const int* __restrict__ offs,
        const int* __restrict__ csr, const float* __restrict__ rdeg,
        float* __restrict__ out, int N) {
    int wid = threadIdx.x >> 6, lane = threadIdx.x & 63;
    int half = lane >> 5, fl = lane & 31;
    int node = blockIdx.x * 8 + wid * 2 + half;
    if (node >= N) return;
    int s0 = offs[node], s1 = offs[node + 1];
    float ax = 0.f, ay = 0.f;
    for (int base = s0; base < s1; base += 32) {
        int cnt = min(32, s1 - base);
        int nid = (fl < cnt) ? csr[base + fl] : 0;
        for (int j = 0; j < cnt; ++j) {
            int s = __shfl(nid, (half << 5) | j, 64);
            unsigned int v = *(const unsigned int*)&z[(size_t)s * 128 + fl * 2];
            ax += __uint_as_float(v << 16);
            ay += __uint_as_float(v & 0xffff0000u);
        }
    }
    float r = rdeg[node];
    unsigned int vr = *(const unsigned int*)&z[(size_t)node * 128 + 64 + fl * 2];
    float2 o;
    o.x = ax * r + __uint_as_float(vr << 16);
    o.y = ay * r + __uint_as_float(vr & 0xffff0000u);
    *(float2*)&out[(size_t)node * 64 + fl * 2] = o;
}

// ---------------- MFMA GEMM (layers 0/1): out = [mean|h] @ Wcat^T + b, relu ----

template <int FOUT, bool RELU>
__global__ __launch_bounds__(256) void gemm_kernel(
        const unsigned short* __restrict__ Abuf,   // mean  [N][128] bf16
        const unsigned short* __restrict__ Hbuf,   // root  [N][128] bf16
        const unsigned short* __restrict__ Wcat,   // [FOUT][256] bf16
        const float* __restrict__ bias,            // [FOUT] fp32
        unsigned short* __restrict__ outb,
        int N) {
    __shared__ unsigned short As[128 * 256];
    __shared__ unsigned short Ws[FOUT * 256];

    const int tid = threadIdx.x;
    const int m0 = blockIdx.x * 128;
    char* Ac = (char*)As;
    char* Wc = (char*)Ws;

    for (int idx = tid; idx < 128 * 16; idx += 256) {
        int row = idx >> 4, kc = idx & 15;
        int g = m0 + row;
        uint4 mv = make_uint4(0u, 0u, 0u, 0u);
        uint4 hv = make_uint4(0u, 0u, 0u, 0u);
        if (g < N) {
            mv = *(const uint4*)&Abuf[(size_t)g * NF + kc * 8];
            hv = *(const uint4*)&Hbuf[(size_t)g * NF + kc * 8];
        }
        int sw = (row & 7) << 4;
        *(uint4*)(Ac + row * 512 + ((kc * 16) ^ sw)) = mv;
        *(uint4*)(Ac + row * 512 + ((256 + kc * 16) ^ sw)) = hv;
    }
    for (int idx = tid; idx < FOUT * 32; idx += 256) {
        int row = idx >> 5, kc = idx & 31;
        uint4 v = *(const uint4*)&Wcat[row * 256 + kc * 8];
        *(uint4*)(Wc + row * 512 + ((kc * 16) ^ ((row & 7) << 4))) = v;
    }
    __syncthreads();

    constexpr int MI = 4;
    constexpr int NI = 4;
    const int wid = tid >> 6, lane = tid & 63;
    const int lm = lane & 15, ko = lane >> 4;
    const int wmBase = (wid >> 1) * 64;
    const int wnBase = (wid & 1) * 64;

    f32x4 acc[MI][NI];
#pragma unroll
    for (int i = 0; i < MI; ++i)
#pragma unroll
        for (int j = 0; j < NI; ++j)
            acc[i][j] = (f32x4){0.f, 0.f, 0.f, 0.f};

#pragma unroll
    for (int ks = 0; ks < 8; ++ks) {
        const int kb = ks * 64 + ko * 16;
        bf16x8 a[MI], b[NI];
#pragma unroll
        for (int i = 0; i < MI; ++i) {
            int row = wmBase + i * 16 + lm;
            a[i] = *(const bf16x8*)(Ac + row * 512 + (kb ^ ((row & 7) << 4)));
        }
#pragma unroll
        for (int j = 0; j < NI; ++j) {
            int row = wnBase + j * 16 + lm;
            b[j] = *(const bf16x8*)(Wc + row * 512 + (kb ^ ((row & 7) << 4)));
        }
#pragma unroll
        for (int i = 0; i < MI; ++i)
#pragma unroll
            for (int j = 0; j < NI; ++j)
                acc[i][j] = __builtin_amdgcn_mfma_f32_16x16x32_bf16(a[i], b[j], acc[i][j], 0, 0, 0);
    }

#pragma unroll
    for (int i = 0; i < MI; ++i) {
        const int rbase = m0 + wmBase + i * 16 + ko * 4;
#pragma unroll
        for (int j = 0; j < NI; ++j) {
            const int col = wnBase + j * 16 + lm;
            const float bv = bias[col];
#pragma unroll
            for (int r = 0; r < 4; ++r) {
                int g = rbase + r;
                if (g >= N) continue;
                float v = acc[i][j][r] + bv;
                if (RELU) v = fmaxf(v, 0.f);
                outb[(size_t)g * FOUT + col] = f2b(v);
            }
        }
    }
}

// ---------------- MFMA GEMM (layer 2): z = h @ Wst^T + bst  (K=128, no relu) ----

__global__ __launch_bounds__(256) void gemmz_kernel(
        const unsigned short* __restrict__ A,    // [N][128] bf16
        const unsigned short* __restrict__ W,    // [128][128] bf16
        const float* __restrict__ bias,          // [128] fp32
        unsigned short* __restrict__ outb,       // [N][128] bf16
        int N) {
    __shared__ unsigned short As[128 * 128];
    __shared__ unsigned short Ws[128 * 128];

    const int tid = threadIdx.x;
    const int m0 = blockIdx.x * 128;
    char* Ac = (char*)As;
    char* Wc = (char*)Ws;

    for (int idx = tid; idx < 128 * 16; idx += 256) {
        int row = idx >> 4, kc = idx & 15;
        int g = m0 + row;
        uint4 v = make_uint4(0u, 0u, 0u, 0u);
        if (g < N) v = *(const uint4*)&A[(size_t)g * 128 + kc * 8];
        *(uint4*)(Ac + row * 256 + ((kc * 16) ^ ((row & 7) << 4))) = v;
    }
    for (int idx = tid; idx < 128 * 16; idx += 256) {
        int row = idx >> 4, kc = idx & 15;
        uint4 v = *(const uint4*)&W[row * 128 + kc * 8];
        *(uint4*)(Wc + row * 256 + ((kc * 16) ^ ((row & 7) << 4))) = v;
    }
    __syncthreads();

    const int wid = tid >> 6, lane = tid & 63;
    const int lm = lane & 15, ko = lane >> 4;
    const int wmBase = (wid >> 1) * 64;
    const int wnBase = (wid & 1) * 64;

    f32x4 acc[4][4];
#pragma unroll
    for (int i = 0; i < 4; ++i)
#pragma unroll
        for (int j = 0; j < 4; ++j)
            acc[i][j] = (f32x4){0.f, 0.f, 0.f, 0.f};

#pragma unroll
    for (int ks = 0; ks < 4; ++ks) {
        const int kb = ks * 64 + ko * 16;
        bf16x8 a[4], b[4];
#pragma unroll
        for (int i = 0; i < 4; ++i) {
            int row = wmBase + i * 16 + lm;
            a[i] = *(const bf16x8*)(Ac + row * 256 + (kb ^ ((row & 7) << 4)));
        }
#pragma unroll
        for (int j = 0; j < 4; ++j) {
            int row = wnBase + j * 16 + lm;
            b[j] = *(const bf16x8*)(Wc + row * 256 + (kb ^ ((row & 7) << 4)));
        }
#pragma unroll
        for (int i = 0; i < 4; ++i)
#pragma unroll
            for (int j = 0; j < 4; ++j)
                acc[i][j] = __builtin_amdgcn_mfma_f32_16x16x32_bf16(a[i], b[j], acc[i][j], 0, 0, 0);
    }

#pragma unroll
    for (int i = 0; i < 4; ++i) {
        const int rbase = m0 + wmBase + i * 16 + ko * 4;
#pragma unroll
        for (int j = 0; j < 4; ++j) {
            const int col = wnBase + j * 16 + lm;
            const float bv = bias[col];
#pragma unroll
            for (int r = 0; r < 4; ++r) {
                int g = rbase + r;
                if (g >= N) continue;
                outb[(size_t)g * 128 + col] = f2b(acc[i][j][r] + bv);
            }
        }
    }
}

// ---------------- launch ----------------

extern "C" void kernel_launch(void* const* d_in, const int* in_sizes, int n_in,
                              void* d_out, int out_size, void* d_ws, size_t ws_size,
                              hipStream_t stream) {
    const float* x   = (const float*)d_in[0];
    const int*   ei  = (const int*)d_in[1];
    const float* Wl0 = (const float*)d_in[2];
    const float* Wr0 = (const float*)d_in[3];
    const float* b0  = (const float*)d_in[4];
    const float* Wl1 = (const float*)d_in[5];
    const float* Wr1 = (const float*)d_in[6];
    const float* b1  = (const float*)d_in[7];
    const float* Wl2 = (const float*)d_in[8];
    const float* Wr2 = (const float*)d_in[9];
    const float* b2  = (const float*)d_in[10];
    float* out = (float*)d_out;

    const int N = in_sizes[0] / NF;
    const int E = in_sizes[1] / 2;
    const int* srcv = ei;
    const int* dstv = ei + E;

    const int NB   = (N + 255) >> 8;        // dst buckets (<=512)
    const int NBLK = (E + CHUNK - 1) / CHUNK;  // edge chunks (<=512)
    const int T    = NB * NBLK;
    const int NS   = (T + 255) / 256;       // <=1024

    char* w = (char*)d_ws;
    auto alloc = [&](size_t bytes) {
        void* p = (void*)w;
        w += (bytes + 255) & ~(size_t)255;
        return p;
    };
    unsigned short* xb   = (unsigned short*)alloc((size_t)N * NF * 2);
    unsigned short* h1b  = (unsigned short*)alloc((size_t)N * NF * 2);
    unsigned short* h2b  = (unsigned short*)alloc((size_t)N * NF * 2);
    unsigned short* mb   = (unsigned short*)alloc((size_t)N * NF * 2);
    unsigned short* z2b  = (unsigned short*)alloc((size_t)N * NF * 2);
    unsigned short* Wc0  = (unsigned short*)alloc((size_t)128 * 256 * 2);
    unsigned short* Wc1  = (unsigned short*)alloc((size_t)128 * 256 * 2);
    unsigned short* Wst2 = (unsigned short*)alloc((size_t)128 * 128 * 2);
    float*          bst2 = (float*)alloc((size_t)128 * 4);
    int*   offs   = (int*)alloc((size_t)(N + 1) * 4);
    int*   csr    = (int*)alloc((size_t)E * 4);
    float* rdeg   = (float*)alloc((size_t)N * 4);
    unsigned int* recs = (unsigned int*)alloc((size_t)E * 4);
    int*   hist   = (int*)alloc((size_t)T * 4);
    int*   base   = (int*)alloc((size_t)T * 4);
    int*   bstart = (int*)alloc((size_t)(NB + 1) * 4);
    int*   sb1    = (int*)alloc((size_t)1024 * 4);
    int*   sb2    = (int*)alloc((size_t)1024 * 4);

    // weight prep + input conversion
    const int n4 = N * NF / 4;
    cvt_kernel<<<(n4 + 255) / 256, 256, 0, stream>>>(x, xb, n4);
    wcat_kernel<<<(128 * 128 + 255) / 256, 256, 0, stream>>>(Wl0, Wr0, Wc0, 128 * 128);
    wcat_kernel<<<(128 * 128 + 255) / 256, 256, 0, stream>>>(Wl1, Wr1, Wc1, 128 * 128);
    wstack_kernel<<<(64 * 128 + 255) / 256, 256, 0, stream>>>(Wl2, Wr2, b2, Wst2, bst2, 64 * 128);

    // CSR build (bucketed counting sort)
    hist_kernel<<<NBLK, 256, 0, stream>>>(dstv, hist, E, NB);
    sb_sum<<<NS, 256, 0, stream>>>(hist, sb1, T, NB, NBLK);
    sb_scan<<<1, 1024, 0, stream>>>(sb1, sb2, NS);
    sb_apply<<<NS, 256, 0, stream>>>(hist, sb2, base, T, NB, NBLK);
    bstart_kernel<<<1, 512, 0, stream>>>(base, bstart, NB, NBLK, E);
    scat_kernel<<<NBLK, 256, 0, stream>>>(srcv, dstv, base, recs, E, NB, NBLK);
    csr_kernel<<<NB, 256, 0, stream>>>(recs, bstart, offs, rdeg, csr, N, E);

    const int ab = (N + 3) / 4;
    const int gb = (N + 127) / 128;

    // layer 0: x(128) -> h1(128), relu
    agg_kernel<<<ab, 256, 0, stream>>>(xb, offs, csr, rdeg, mb, N);
    gemm_kernel<128, true><<<gb, 256, 0, stream>>>(mb, xb, Wc0, b0, h1b, N);

    // layer 1: h1(128) -> h2(128), relu
    agg_kernel<<<ab, 256, 0, stream>>>(h1b, offs, csr, rdeg, mb, N);
    gemm_kernel<128, true><<<gb, 256, 0, stream>>>(mb, h1b, Wc1, b1, h2b, N);

    // layer 2 (transform-before-aggregate): z=[h2@Wl2^T | h2@Wr2^T+b2], out=agg(zl)+zr
    gemmz_kernel<<<gb, 256, 0, stream>>>(h2b, Wst2, bst2, z2b, N);
    agg2_kernel<<<(N + 7) / 8, 256, 0, stream>>>(z2b, offs, csr, rdeg, out, N);
}

// Round 5
// 343.939 us; speedup vs baseline: 5.0543x; 1.3527x over previous
//
#include <hip/hip_runtime.h>

#define NF 128      // feature width for x / hidden layers
#define CHUNK 4096  // edges per block in CSR-build phase 1

typedef __attribute__((ext_vector_type(8))) short bf16x8;
typedef __attribute__((ext_vector_type(4))) float f32x4;

__device__ __forceinline__ unsigned short f2b(float f) {
    unsigned int u = __float_as_uint(f);
    unsigned int r = (u + 0x7fffu + ((u >> 16) & 1u)) >> 16;  // round-nearest-even
    return (unsigned short)r;
}

// ================= CSR build: bucketed two-phase counting sort =================

__global__ __launch_bounds__(256) void hist_kernel(const int* __restrict__ dst,
                                                   int* __restrict__ hist,
                                                   int E, int NB) {
    __shared__ int h[512];
    const int blk = blockIdx.x;
    for (int i = threadIdx.x; i < NB; i += 256) h[i] = 0;
    __syncthreads();
    const int e0 = blk * CHUNK;
    for (int i = threadIdx.x; i < CHUNK; i += 256) {
        int e = e0 + i;
        if (e < E) atomicAdd(&h[dst[e] >> 8], 1);
    }
    __syncthreads();
    for (int i = threadIdx.x; i < NB; i += 256) hist[blk * NB + i] = h[i];
}

__global__ __launch_bounds__(256) void sb_sum(const int* __restrict__ hist,
                                              int* __restrict__ bsum,
                                              int T, int NB, int NBLK) {
    int i = blockIdx.x * 256 + threadIdx.x;
    int v = 0;
    if (i < T) {
        int b = i / NBLK, blk = i - b * NBLK;
        v = hist[blk * NB + b];
    }
#pragma unroll
    for (int d = 32; d; d >>= 1) v += __shfl_down(v, d, 64);
    __shared__ int wsum[4];
    if ((threadIdx.x & 63) == 0) wsum[threadIdx.x >> 6] = v;
    __syncthreads();
    if (threadIdx.x == 0) bsum[blockIdx.x] = wsum[0] + wsum[1] + wsum[2] + wsum[3];
}

__global__ __launch_bounds__(1024) void sb_scan(const int* __restrict__ bsum,
                                                int* __restrict__ bpre, int NS) {
    __shared__ int s[1024];
    int t = threadIdx.x;
    int v = (t < NS) ? bsum[t] : 0;
    s[t] = v;
    __syncthreads();
    for (int d = 1; d < 1024; d <<= 1) {
        int u = (t >= d) ? s[t - d] : 0;
        __syncthreads();
        s[t] += u;
        __syncthreads();
    }
    if (t < NS) bpre[t] = s[t] - v;
}

__global__ __launch_bounds__(256) void sb_apply(const int* __restrict__ hist,
                                                const int* __restrict__ bpre,
                                                int* __restrict__ base,
                                                int T, int NB, int NBLK) {
    __shared__ int s[256];
    int i = blockIdx.x * 256 + threadIdx.x;
    int t = threadIdx.x;
    int v = 0;
    if (i < T) {
        int b = i / NBLK, blk = i - b * NBLK;
        v = hist[blk * NB + b];
    }
    s[t] = v;
    __syncthreads();
    for (int d = 1; d < 256; d <<= 1) {
        int u = (t >= d) ? s[t - d] : 0;
        __syncthreads();
        s[t] += u;
        __syncthreads();
    }
    if (i < T) base[i] = bpre[blockIdx.x] + s[t] - v;
}

__global__ __launch_bounds__(512) void bstart_kernel(const int* __restrict__ base,
                                                     int* __restrict__ bstart,
                                                     int NB, int NBLK, int E) {
    int i = threadIdx.x;
    if (i < NB) bstart[i] = base[i * NBLK];
    if (i == NB) bstart[i] = E;
}

__global__ __launch_bounds__(256) void scat_kernel(const int* __restrict__ src,
                                                   const int* __restrict__ dst,
                                                   const int* __restrict__ base,
                                                   unsigned int* __restrict__ recs,
                                                   int E, int NB, int NBLK) {
    __shared__ int cur[512];
    const int blk = blockIdx.x;
    for (int b = threadIdx.x; b < NB; b += 256) cur[b] = base[b * NBLK + blk];
    __syncthreads();
    const int e0 = blk * CHUNK;
    for (int i = threadIdx.x; i < CHUNK; i += 256) {
        int e = e0 + i;
        if (e >= E) continue;
        int d = dst[e];
        int b = d >> 8;
        int pos = atomicAdd(&cur[b], 1);
        recs[pos] = (unsigned int)src[e] | ((unsigned int)(d & 255) << 24);
    }
}

__global__ __launch_bounds__(256) void csr_kernel(const unsigned int* __restrict__ recs,
                                                  const int* __restrict__ bstart,
                                                  int* __restrict__ offs,
                                                  float* __restrict__ rdeg,
                                                  int* __restrict__ csr,
                                                  int N, int E) {
    __shared__ int cnt[256];
    __shared__ int sc[256];
    __shared__ int cur[256];
    const int b = blockIdx.x;
    const int t = threadIdx.x;
    const int s0 = bstart[b], s1 = bstart[b + 1];
    cnt[t] = 0;
    __syncthreads();
    for (int i = s0 + t; i < s1; i += 256) atomicAdd(&cnt[recs[i] >> 24], 1);
    __syncthreads();
    int v = cnt[t];
    sc[t] = v;
    __syncthreads();
    for (int d = 1; d < 256; d <<= 1) {
        int u = (t >= d) ? sc[t - d] : 0;
        __syncthreads();
        sc[t] += u;
        __syncthreads();
    }
    int excl = sc[t] - v;
    int node = b * 256 + t;
    if (node < N) {
        offs[node] = s0 + excl;
        rdeg[node] = 1.0f / (float)(v > 1 ? v : 1);
        if (node == N - 1) offs[N] = E;
    }
    cur[t] = s0 + excl;
    __syncthreads();
    for (int i = s0 + t; i < s1; i += 256) {
        unsigned int r = recs[i];
        int pos = atomicAdd(&cur[r >> 24], 1);
        csr[pos] = (int)(r & 0xFFFFFFu);
    }
}

// ---------------- fp32 -> bf16 conversions ----------------

__global__ void cvt_kernel(const float* __restrict__ x, unsigned short* __restrict__ xb, int n4) {
    int i = blockIdx.x * 256 + threadIdx.x;
    if (i >= n4) return;
    float4 v = *(const float4*)&x[(size_t)i * 4];
    uint2 o;
    o.x = (unsigned int)f2b(v.x) | ((unsigned int)f2b(v.y) << 16);
    o.y = (unsigned int)f2b(v.z) | ((unsigned int)f2b(v.w) << 16);
    *(uint2*)&xb[(size_t)i * 4] = o;
}

__global__ void wcat_kernel(const float* __restrict__ Wl, const float* __restrict__ Wr,
                            unsigned short* __restrict__ Wc, int total /*128*128*/) {
    int i = blockIdx.x * 256 + threadIdx.x;
    if (i >= total) return;
    int f = i >> 7, k = i & 127;
    Wc[f * 256 + k] = f2b(Wl[i]);
    Wc[f * 256 + 128 + k] = f2b(Wr[i]);
}

__global__ void wstack_kernel(const float* __restrict__ Wl, const float* __restrict__ Wr,
                              const float* __restrict__ b2,
                              unsigned short* __restrict__ Wst, float* __restrict__ bst,
                              int total /*64*128*/) {
    int i = blockIdx.x * 256 + threadIdx.x;
    if (i >= total) return;
    int f = i >> 7, k = i & 127;
    Wst[f * 128 + k] = f2b(Wl[i]);
    Wst[(f + 64) * 128 + k] = f2b(Wr[i]);
    if (k == 0) {
        bst[f] = 0.f;
        bst[f + 64] = b2[f];
    }
}

// ---------------- mean aggregation (bf16 in/out), batched-MLP gather ----------

__global__ __launch_bounds__(256) void agg_kernel(
        const unsigned short* __restrict__ h, const int* __restrict__ offs,
        const int* __restrict__ csr, const float* __restrict__ rdeg,
        unsigned short* __restrict__ meanout, int N) {
    int node = blockIdx.x * 4 + (threadIdx.x >> 6);
    int lane = threadIdx.x & 63;
    if (node >= N) return;
    int s0 = offs[node], s1 = offs[node + 1];
    float ax = 0.f, ay = 0.f;
    for (int base = s0; base < s1; base += 64) {
        int cnt = min(64, s1 - base);
        int nid = csr[base + min(lane, cnt - 1)];  // clamped: trailing lanes replicate
        int j = 0;
        for (; j + 8 <= cnt; j += 8) {
            int sj[8];
#pragma unroll
            for (int k = 0; k < 8; ++k) sj[k] = __shfl(nid, j + k, 64);
            unsigned int v[8];
#pragma unroll
            for (int k = 0; k < 8; ++k)
                v[k] = *(const unsigned int*)&h[(size_t)sj[k] * NF + lane * 2];
#pragma unroll
            for (int k = 0; k < 8; ++k) {
                ax += __uint_as_float(v[k] << 16);
                ay += __uint_as_float(v[k] & 0xffff0000u);
            }
        }
        if (j < cnt) {  // tail group (<8), predicated accumulate, clamped ids
            int sj[8];
#pragma unroll
            for (int k = 0; k < 8; ++k) sj[k] = __shfl(nid, min(j + k, cnt - 1), 64);
            unsigned int v[8];
#pragma unroll
            for (int k = 0; k < 8; ++k)
                v[k] = *(const unsigned int*)&h[(size_t)sj[k] * NF + lane * 2];
#pragma unroll
            for (int k = 0; k < 8; ++k) {
                if (j + k < cnt) {
                    ax += __uint_as_float(v[k] << 16);
                    ay += __uint_as_float(v[k] & 0xffff0000u);
                }
            }
        }
    }
    float r = rdeg[node];
    unsigned int o = (unsigned int)f2b(ax * r) | ((unsigned int)f2b(ay * r) << 16);
    *(unsigned int*)&meanout[(size_t)node * NF + lane * 2] = o;
}

// ---- layer-2 final aggregation: out[i] = mean_j zl[j] + zr[i]  (fp32 out) ----

__global__ __launch_bounds__(256) void agg2_kernel(
        const unsigned short* __restrict__ z, const int* __restrict__ offs,
        const int* __restrict__ csr, const float* __restrict__ rdeg,
        float* __restrict__ out, int N) {
    int wid = threadIdx.x >> 6, lane = threadIdx.x & 63;
    int half = lane >> 5, fl = lane & 31;
    int node = blockIdx.x * 8 + wid * 2 + half;
    if (node >= N) return;
    int s0 = offs[node], s1 = offs[node + 1];
    float ax = 0.f, ay = 0.f;
    for (int base = s0; base < s1; base += 32) {
        int cnt = min(32, s1 - base);
        int nid = csr[base + min(fl, cnt - 1)];
        int j = 0;
        for (; j + 8 <= cnt; j += 8) {
            int sj[8];
#pragma unroll
            for (int k = 0; k < 8; ++k) sj[k] = __shfl(nid, (half << 5) | (j + k), 64);
            unsigned int v[8];
#pragma unroll
            for (int k = 0; k < 8; ++k)
                v[k] = *(const unsigned int*)&z[(size_t)sj[k] * 128 + fl * 2];
#pragma unroll
            for (int k = 0; k < 8; ++k) {
                ax += __uint_as_float(v[k] << 16);
                ay += __uint_as_float(v[k] & 0xffff0000u);
            }
        }
        if (j < cnt) {
            int sj[8];
#pragma unroll
            for (int k = 0; k < 8; ++k) sj[k] = __shfl(nid, (half << 5) | min(j + k, cnt - 1), 64);
            unsigned int v[8];
#pragma unroll
            for (int k = 0; k < 8; ++k)
                v[k] = *(const unsigned int*)&z[(size_t)sj[k] * 128 + fl * 2];
#pragma unroll
            for (int k = 0; k < 8; ++k) {
                if (j + k < cnt) {
                    ax += __uint_as_float(v[k] << 16);
                    ay += __uint_as_float(v[k] & 0xffff0000u);
                }
            }
        }
    }
    float r = rdeg[node];
    unsigned int vr = *(const unsigned int*)&z[(size_t)node * 128 + 64 + fl * 2];
    float2 o;
    o.x = ax * r + __uint_as_float(vr << 16);
    o.y = ay * r + __uint_as_float(vr & 0xffff0000u);
    *(float2*)&out[(size_t)node * 64 + fl * 2] = o;
}

// ---------------- MFMA GEMM (layers 0/1): out = [mean|h] @ Wcat^T + b, relu ----

template <int FOUT, bool RELU>
__global__ __launch_bounds__(256) void gemm_kernel(
        const unsigned short* __restrict__ Abuf,
        const unsigned short* __restrict__ Hbuf,
        const unsigned short* __restrict__ Wcat,
        const float* __restrict__ bias,
        unsigned short* __restrict__ outb,
        int N) {
    __shared__ unsigned short As[128 * 256];
    __shared__ unsigned short Ws[FOUT * 256];

    const int tid = threadIdx.x;
    const int m0 = blockIdx.x * 128;
    char* Ac = (char*)As;
    char* Wc = (char*)Ws;

    for (int idx = tid; idx < 128 * 16; idx += 256) {
        int row = idx >> 4, kc = idx & 15;
        int g = m0 + row;
        uint4 mv = make_uint4(0u, 0u, 0u, 0u);
        uint4 hv = make_uint4(0u, 0u, 0u, 0u);
        if (g < N) {
            mv = *(const uint4*)&Abuf[(size_t)g * NF + kc * 8];
            hv = *(const uint4*)&Hbuf[(size_t)g * NF + kc * 8];
        }
        int sw = (row & 7) << 4;
        *(uint4*)(Ac + row * 512 + ((kc * 16) ^ sw)) = mv;
        *(uint4*)(Ac + row * 512 + ((256 + kc * 16) ^ sw)) = hv;
    }
    for (int idx = tid; idx < FOUT * 32; idx += 256) {
        int row = idx >> 5, kc = idx & 31;
        uint4 v = *(const uint4*)&Wcat[row * 256 + kc * 8];
        *(uint4*)(Wc + row * 512 + ((kc * 16) ^ ((row & 7) << 4))) = v;
    }
    __syncthreads();

    constexpr int MI = 4;
    constexpr int NI = 4;
    const int wid = tid >> 6, lane = tid & 63;
    const int lm = lane & 15, ko = lane >> 4;
    const int wmBase = (wid >> 1) * 64;
    const int wnBase = (wid & 1) * 64;

    f32x4 acc[MI][NI];
#pragma unroll
    for (int i = 0; i < MI; ++i)
#pragma unroll
        for (int j = 0; j < NI; ++j)
            acc[i][j] = (f32x4){0.f, 0.f, 0.f, 0.f};

#pragma unroll
    for (int ks = 0; ks < 8; ++ks) {
        const int kb = ks * 64 + ko * 16;
        bf16x8 a[MI], b[NI];
#pragma unroll
        for (int i = 0; i < MI; ++i) {
            int row = wmBase + i * 16 + lm;
            a[i] = *(const bf16x8*)(Ac + row * 512 + (kb ^ ((row & 7) << 4)));
        }
#pragma unroll
        for (int j = 0; j < NI; ++j) {
            int row = wnBase + j * 16 + lm;
            b[j] = *(const bf16x8*)(Wc + row * 512 + (kb ^ ((row & 7) << 4)));
        }
#pragma unroll
        for (int i = 0; i < MI; ++i)
#pragma unroll
            for (int j = 0; j < NI; ++j)
                acc[i][j] = __builtin_amdgcn_mfma_f32_16x16x32_bf16(a[i], b[j], acc[i][j], 0, 0, 0);
    }

#pragma unroll
    for (int i = 0; i < MI; ++i) {
        const int rbase = m0 + wmBase + i * 16 + ko * 4;
#pragma unroll
        for (int j = 0; j < NI; ++j) {
            const int col = wnBase + j * 16 + lm;
            const float bv = bias[col];
#pragma unroll
            for (int r = 0; r < 4; ++r) {
                int g = rbase + r;
                if (g >= N) continue;
                float v = acc[i][j][r] + bv;
                if (RELU) v = fmaxf(v, 0.f);
                outb[(size_t)g * FOUT + col] = f2b(v);
            }
        }
    }
}

// ---------------- MFMA GEMM (layer 2): z = h @ Wst^T + bst  (K=128) ----------

__global__ __launch_bounds__(256) void gemmz_kernel(
        const unsigned short* __restrict__ A,
        const unsigned short* __restrict__ W,
        const float* __restrict__ bias,
        unsigned short* __restrict__ outb,
        int N) {
    __shared__ unsigned short As[128 * 128];
    __shared__ unsigned short Ws[128 * 128];

    const int tid = threadIdx.x;
    const int m0 = blockIdx.x * 128;
    char* Ac = (char*)As;
    char* Wc = (char*)Ws;

    for (int idx = tid; idx < 128 * 16; idx += 256) {
        int row = idx >> 4, kc = idx & 15;
        int g = m0 + row;
        uint4 v = make_uint4(0u, 0u, 0u, 0u);
        if (g < N) v = *(const uint4*)&A[(size_t)g * 128 + kc * 8];
        *(uint4*)(Ac + row * 256 + ((kc * 16) ^ ((row & 7) << 4))) = v;
    }
    for (int idx = tid; idx < 128 * 16; idx += 256) {
        int row = idx >> 4, kc = idx & 15;
        uint4 v = *(const uint4*)&W[row * 128 + kc * 8];
        *(uint4*)(Wc + row * 256 + ((kc * 16) ^ ((row & 7) << 4))) = v;
    }
    __syncthreads();

    const int wid = tid >> 6, lane = tid & 63;
    const int lm = lane & 15, ko = lane >> 4;
    const int wmBase = (wid >> 1) * 64;
    const int wnBase = (wid & 1) * 64;

    f32x4 acc[4][4];
#pragma unroll
    for (int i = 0; i < 4; ++i)
#pragma unroll
        for (int j = 0; j < 4; ++j)
            acc[i][j] = (f32x4){0.f, 0.f, 0.f, 0.f};

#pragma unroll
    for (int ks = 0; ks < 4; ++ks) {
        const int kb = ks * 64 + ko * 16;
        bf16x8 a[4], b[4];
#pragma unroll
        for (int i = 0; i < 4; ++i) {
            int row = wmBase + i * 16 + lm;
            a[i] = *(const bf16x8*)(Ac + row * 256 + (kb ^ ((row & 7) << 4)));
        }
#pragma unroll
        for (int j = 0; j < 4; ++j) {
            int row = wnBase + j * 16 + lm;
            b[j] = *(const bf16x8*)(Wc + row * 256 + (kb ^ ((row & 7) << 4)));
        }
#pragma unroll
        for (int i = 0; i < 4; ++i)
#pragma unroll
            for (int j = 0; j < 4; ++j)
                acc[i][j] = __builtin_amdgcn_mfma_f32_16x16x32_bf16(a[i], b[j], acc[i][j], 0, 0, 0);
    }

#pragma unroll
    for (int i = 0; i < 4; ++i) {
        const int rbase = m0 + wmBase + i * 16 + ko * 4;
#pragma unroll
        for (int j = 0; j < 4; ++j) {
            const int col = wnBase + j * 16 + lm;
            const float bv = bias[col];
#pragma unroll
            for (int r = 0; r < 4; ++r) {
                int g = rbase + r;
                if (g >= N) continue;
                outb[(size_t)g * 128 + col] = f2b(acc[i][j][r] + bv);
            }
        }
    }
}

// ---------------- launch ----------------

extern "C" void kernel_launch(void* const* d_in, const int* in_sizes, int n_in,
                              void* d_out, int out_size, void* d_ws, size_t ws_size,
                              hipStream_t stream) {
    const float* x   = (const float*)d_in[0];
    const int*   ei  = (const int*)d_in[1];
    const float* Wl0 = (const float*)d_in[2];
    const float* Wr0 = (const float*)d_in[3];
    const float* b0  = (const float*)d_in[4];
    const float* Wl1 = (const float*)d_in[5];
    const float* Wr1 = (const float*)d_in[6];
    const float* b1  = (const float*)d_in[7];
    const float* Wl2 = (const float*)d_in[8];
    const float* Wr2 = (const float*)d_in[9];
    const float* b2  = (const float*)d_in[10];
    float* out = (float*)d_out;

    const int N = in_sizes[0] / NF;
    const int E = in_sizes[1] / 2;
    const int* srcv = ei;
    const int* dstv = ei + E;

    const int NB   = (N + 255) >> 8;
    const int NBLK = (E + CHUNK - 1) / CHUNK;
    const int T    = NB * NBLK;
    const int NS   = (T + 255) / 256;

    char* w = (char*)d_ws;
    auto alloc = [&](size_t bytes) {
        void* p = (void*)w;
        w += (bytes + 255) & ~(size_t)255;
        return p;
    };
    unsigned short* xb   = (unsigned short*)alloc((size_t)N * NF * 2);
    unsigned short* h1b  = (unsigned short*)alloc((size_t)N * NF * 2);
    unsigned short* h2b  = (unsigned short*)alloc((size_t)N * NF * 2);
    unsigned short* mb   = (unsigned short*)alloc((size_t)N * NF * 2);
    unsigned short* z2b  = (unsigned short*)alloc((size_t)N * NF * 2);
    unsigned short* Wc0  = (unsigned short*)alloc((size_t)128 * 256 * 2);
    unsigned short* Wc1  = (unsigned short*)alloc((size_t)128 * 256 * 2);
    unsigned short* Wst2 = (unsigned short*)alloc((size_t)128 * 128 * 2);
    float*          bst2 = (float*)alloc((size_t)128 * 4);
    int*   offs   = (int*)alloc((size_t)(N + 1) * 4);
    int*   csr    = (int*)alloc((size_t)E * 4);
    float* rdeg   = (float*)alloc((size_t)N * 4);
    unsigned int* recs = (unsigned int*)alloc((size_t)E * 4);
    int*   hist   = (int*)alloc((size_t)T * 4);
    int*   base   = (int*)alloc((size_t)T * 4);
    int*   bstart = (int*)alloc((size_t)(NB + 1) * 4);
    int*   sb1    = (int*)alloc((size_t)1024 * 4);
    int*   sb2    = (int*)alloc((size_t)1024 * 4);

    const int n4 = N * NF / 4;
    cvt_kernel<<<(n4 + 255) / 256, 256, 0, stream>>>(x, xb, n4);
    wcat_kernel<<<(128 * 128 + 255) / 256, 256, 0, stream>>>(Wl0, Wr0, Wc0, 128 * 128);
    wcat_kernel<<<(128 * 128 + 255) / 256, 256, 0, stream>>>(Wl1, Wr1, Wc1, 128 * 128);
    wstack_kernel<<<(64 * 128 + 255) / 256, 256, 0, stream>>>(Wl2, Wr2, b2, Wst2, bst2, 64 * 128);

    hist_kernel<<<NBLK, 256, 0, stream>>>(dstv, hist, E, NB);
    sb_sum<<<NS, 256, 0, stream>>>(hist, sb1, T, NB, NBLK);
    sb_scan<<<1, 1024, 0, stream>>>(sb1, sb2, NS);
    sb_apply<<<NS, 256, 0, stream>>>(hist, sb2, base, T, NB, NBLK);
    bstart_kernel<<<1, 512, 0, stream>>>(base, bstart, NB, NBLK, E);
    scat_kernel<<<NBLK, 256, 0, stream>>>(srcv, dstv, base, recs, E, NB, NBLK);
    csr_kernel<<<NB, 256, 0, stream>>>(recs, bstart, offs, rdeg, csr, N, E);

    const int ab = (N + 3) / 4;
    const int gb = (N + 127) / 128;

    agg_kernel<<<ab, 256, 0, stream>>>(xb, offs, csr, rdeg, mb, N);
    gemm_kernel<128, true><<<gb, 256, 0, stream>>>(mb, xb, Wc0, b0, h1b, N);

    agg_kernel<<<ab, 256, 0, stream>>>(h1b, offs, csr, rdeg, mb, N);
    gemm_kernel<128, true><<<gb, 256, 0, stream>>>(mb, h1b, Wc1, b1, h2b, N);

    gemmz_kernel<<<gb, 256, 0, stream>>>(h2b, Wst2, bst2, z2b, N);
    agg2_kernel<<<(N + 7) / 8, 256, 0, stream>>>(z2b, offs, csr, rdeg, out, N);
}

// Round 6
// 311.577 us; speedup vs baseline: 5.5792x; 1.1039x over previous
//
#include <hip/hip_runtime.h>

#define NF 128      // feature width for x / hidden layers
#define CHUNK 4096  // edges per block in CSR-build phase 1

typedef __attribute__((ext_vector_type(8))) short bf16x8;
typedef __attribute__((ext_vector_type(4))) float f32x4;
typedef __attribute__((ext_vector_type(2))) float f32x2;

__device__ __forceinline__ unsigned short f2b(float f) {
    unsigned int u = __float_as_uint(f);
    unsigned int r = (u + 0x7fffu + ((u >> 16) & 1u)) >> 16;  // round-nearest-even
    return (unsigned short)r;
}

// async global->LDS, 16B per lane. LDS dest = wave-uniform base (+lane*16 by HW);
// global src is per-lane. Casts go through integers (addrspace rules).
__device__ __forceinline__ void gld_lds16(const void* g, const void* l) {
    __builtin_amdgcn_global_load_lds(
        (const __attribute__((address_space(1))) unsigned int*)(unsigned long long)g,
        (__attribute__((address_space(3))) unsigned int*)(unsigned int)(unsigned long long)l,
        16, 0, 0);
}

// ================= CSR build: bucketed two-phase counting sort =================

__global__ __launch_bounds__(256) void hist_kernel(const int* __restrict__ dst,
                                                   int* __restrict__ hist,
                                                   int E, int NB) {
    __shared__ int h[512];
    const int blk = blockIdx.x;
    for (int i = threadIdx.x; i < NB; i += 256) h[i] = 0;
    __syncthreads();
    const int e0 = blk * CHUNK;
    for (int i = threadIdx.x; i < CHUNK; i += 256) {
        int e = e0 + i;
        if (e < E) atomicAdd(&h[dst[e] >> 8], 1);
    }
    __syncthreads();
    for (int i = threadIdx.x; i < NB; i += 256) hist[blk * NB + i] = h[i];
}

__global__ __launch_bounds__(256) void sb_sum(const int* __restrict__ hist,
                                              int* __restrict__ bsum,
                                              int T, int NB, int NBLK) {
    int i = blockIdx.x * 256 + threadIdx.x;
    int v = 0;
    if (i < T) {
        int b = i / NBLK, blk = i - b * NBLK;
        v = hist[blk * NB + b];
    }
#pragma unroll
    for (int d = 32; d; d >>= 1) v += __shfl_down(v, d, 64);
    __shared__ int wsum[4];
    if ((threadIdx.x & 63) == 0) wsum[threadIdx.x >> 6] = v;
    __syncthreads();
    if (threadIdx.x == 0) bsum[blockIdx.x] = wsum[0] + wsum[1] + wsum[2] + wsum[3];
}

__global__ __launch_bounds__(1024) void sb_scan(const int* __restrict__ bsum,
                                                int* __restrict__ bpre, int NS) {
    __shared__ int s[1024];
    int t = threadIdx.x;
    int v = (t < NS) ? bsum[t] : 0;
    s[t] = v;
    __syncthreads();
    for (int d = 1; d < 1024; d <<= 1) {
        int u = (t >= d) ? s[t - d] : 0;
        __syncthreads();
        s[t] += u;
        __syncthreads();
    }
    if (t < NS) bpre[t] = s[t] - v;
}

__global__ __launch_bounds__(256) void sb_apply(const int* __restrict__ hist,
                                                const int* __restrict__ bpre,
                                                int* __restrict__ base,
                                                int T, int NB, int NBLK) {
    __shared__ int s[256];
    int i = blockIdx.x * 256 + threadIdx.x;
    int t = threadIdx.x;
    int v = 0;
    if (i < T) {
        int b = i / NBLK, blk = i - b * NBLK;
        v = hist[blk * NB + b];
    }
    s[t] = v;
    __syncthreads();
    for (int d = 1; d < 256; d <<= 1) {
        int u = (t >= d) ? s[t - d] : 0;
        __syncthreads();
        s[t] += u;
        __syncthreads();
    }
    if (i < T) base[i] = bpre[blockIdx.x] + s[t] - v;
}

__global__ __launch_bounds__(512) void bstart_kernel(const int* __restrict__ base,
                                                     int* __restrict__ bstart,
                                                     int NB, int NBLK, int E) {
    int i = threadIdx.x;
    if (i < NB) bstart[i] = base[i * NBLK];
    if (i == NB) bstart[i] = E;
}

__global__ __launch_bounds__(256) void scat_kernel(const int* __restrict__ src,
                                                   const int* __restrict__ dst,
                                                   const int* __restrict__ base,
                                                   unsigned int* __restrict__ recs,
                                                   int E, int NB, int NBLK) {
    __shared__ int cur[512];
    const int blk = blockIdx.x;
    for (int b = threadIdx.x; b < NB; b += 256) cur[b] = base[b * NBLK + blk];
    __syncthreads();
    const int e0 = blk * CHUNK;
    for (int i = threadIdx.x; i < CHUNK; i += 256) {
        int e = e0 + i;
        if (e >= E) continue;
        int d = dst[e];
        int b = d >> 8;
        int pos = atomicAdd(&cur[b], 1);
        recs[pos] = (unsigned int)src[e] | ((unsigned int)(d & 255) << 24);
    }
}

__global__ __launch_bounds__(256) void csr_kernel(const unsigned int* __restrict__ recs,
                                                  const int* __restrict__ bstart,
                                                  int* __restrict__ offs,
                                                  float* __restrict__ rdeg,
                                                  int* __restrict__ csr,
                                                  int N, int E) {
    __shared__ int cnt[256];
    __shared__ int sc[256];
    __shared__ int cur[256];
    const int b = blockIdx.x;
    const int t = threadIdx.x;
    const int s0 = bstart[b], s1 = bstart[b + 1];
    cnt[t] = 0;
    __syncthreads();
    for (int i = s0 + t; i < s1; i += 256) atomicAdd(&cnt[recs[i] >> 24], 1);
    __syncthreads();
    int v = cnt[t];
    sc[t] = v;
    __syncthreads();
    for (int d = 1; d < 256; d <<= 1) {
        int u = (t >= d) ? sc[t - d] : 0;
        __syncthreads();
        sc[t] += u;
        __syncthreads();
    }
    int excl = sc[t] - v;
    int node = b * 256 + t;
    if (node < N) {
        offs[node] = s0 + excl;
        rdeg[node] = 1.0f / (float)(v > 1 ? v : 1);
        if (node == N - 1) offs[N] = E;
    }
    cur[t] = s0 + excl;
    __syncthreads();
    for (int i = s0 + t; i < s1; i += 256) {
        unsigned int r = recs[i];
        int pos = atomicAdd(&cur[r >> 24], 1);
        csr[pos] = (int)(r & 0xFFFFFFu);
    }
}

// ---------------- fp32 -> bf16 conversions ----------------

__global__ void cvt_kernel(const float* __restrict__ x, unsigned short* __restrict__ xb, int n4) {
    int i = blockIdx.x * 256 + threadIdx.x;
    if (i >= n4) return;
    float4 v = *(const float4*)&x[(size_t)i * 4];
    uint2 o;
    o.x = (unsigned int)f2b(v.x) | ((unsigned int)f2b(v.y) << 16);
    o.y = (unsigned int)f2b(v.z) | ((unsigned int)f2b(v.w) << 16);
    *(uint2*)&xb[(size_t)i * 4] = o;
}

__global__ void wcat_kernel(const float* __restrict__ Wl, const float* __restrict__ Wr,
                            unsigned short* __restrict__ Wc, int total /*128*128*/) {
    int i = blockIdx.x * 256 + threadIdx.x;
    if (i >= total) return;
    int f = i >> 7, k = i & 127;
    Wc[f * 256 + k] = f2b(Wl[i]);
    Wc[f * 256 + 128 + k] = f2b(Wr[i]);
}

__global__ void wstack_kernel(const float* __restrict__ Wl, const float* __restrict__ Wr,
                              const float* __restrict__ b2,
                              unsigned short* __restrict__ Wst, float* __restrict__ bst,
                              int total /*64*128*/) {
    int i = blockIdx.x * 256 + threadIdx.x;
    if (i >= total) return;
    int f = i >> 7, k = i & 127;
    Wst[f * 128 + k] = f2b(Wl[i]);
    Wst[(f + 64) * 128 + k] = f2b(Wr[i]);
    if (k == 0) {
        bst[f] = 0.f;
        bst[f + 64] = b2[f];
    }
}

// -------- mean aggregation (bf16 in/out): one node/wave, uint2 gather --------
// 32 lanes cover a 256B row; halves process alternate edges; f32x2 packed adds.

__global__ __launch_bounds__(256) void agg_kernel(
        const unsigned short* __restrict__ h, const int* __restrict__ offs,
        const int* __restrict__ csr, const float* __restrict__ rdeg,
        unsigned short* __restrict__ meanout, int N) {
    const int node = blockIdx.x * 4 + (threadIdx.x >> 6);
    const int lane = threadIdx.x & 63;
    if (node >= N) return;
    const int hlf = lane >> 5;   // which edge of a pair
    const int fl  = lane & 31;   // features fl*4 .. fl*4+3
    const int s0 = offs[node], s1 = offs[node + 1];
    f32x2 a0 = {0.f, 0.f}, a1 = {0.f, 0.f};
    for (int base = s0; base < s1; base += 64) {
        const int cnt = min(64, s1 - base);
        const int nid = csr[base + min(lane, cnt - 1)];
        int j = 0;
        for (; j + 16 <= cnt; j += 16) {  // 16 edges: 8 loads in flight
            int sj[8];
#pragma unroll
            for (int k = 0; k < 8; ++k) sj[k] = __shfl(nid, j + 2 * k + hlf, 64);
            uint2 v[8];
#pragma unroll
            for (int k = 0; k < 8; ++k)
                v[k] = *(const uint2*)&h[(size_t)sj[k] * NF + fl * 4];
#pragma unroll
            for (int k = 0; k < 8; ++k) {
                a0 += (f32x2){__uint_as_float(v[k].x << 16), __uint_as_float(v[k].x & 0xffff0000u)};
                a1 += (f32x2){__uint_as_float(v[k].y << 16), __uint_as_float(v[k].y & 0xffff0000u)};
            }
        }
        for (; j < cnt; j += 4) {  // tail: 4-edge rounds, predicated
#pragma unroll
            for (int k = 0; k < 2; ++k) {
                int idx = j + 2 * k + hlf;
                int sj = __shfl(nid, min(idx, cnt - 1), 64);
                uint2 v = *(const uint2*)&h[(size_t)sj * NF + fl * 4];
                if (idx < cnt) {
                    a0 += (f32x2){__uint_as_float(v.x << 16), __uint_as_float(v.x & 0xffff0000u)};
                    a1 += (f32x2){__uint_as_float(v.y << 16), __uint_as_float(v.y & 0xffff0000u)};
                }
            }
        }
    }
    a0.x += __shfl_xor(a0.x, 32, 64);
    a0.y += __shfl_xor(a0.y, 32, 64);
    a1.x += __shfl_xor(a1.x, 32, 64);
    a1.y += __shfl_xor(a1.y, 32, 64);
    if (hlf == 0) {
        float r = rdeg[node];
        uint2 o;
        o.x = (unsigned int)f2b(a0.x * r) | ((unsigned int)f2b(a0.y * r) << 16);
        o.y = (unsigned int)f2b(a1.x * r) | ((unsigned int)f2b(a1.y * r) << 16);
        *(uint2*)&meanout[(size_t)node * NF + fl * 4] = o;
    }
}

// ---- layer-2 final agg: out[i] = mean_j zl[j] + zr[i]; one node/wave, 16-lane rows

__global__ __launch_bounds__(256) void agg2_kernel(
        const unsigned short* __restrict__ z, const int* __restrict__ offs,
        const int* __restrict__ csr, const float* __restrict__ rdeg,
        float* __restrict__ out, int N) {
    const int node = blockIdx.x * 4 + (threadIdx.x >> 6);
    const int lane = threadIdx.x & 63;
    if (node >= N) return;
    const int q  = lane >> 4;   // which edge of a quad
    const int fl = lane & 15;   // features fl*4 .. fl*4+3
    const int s0 = offs[node], s1 = offs[node + 1];
    f32x2 a0 = {0.f, 0.f}, a1 = {0.f, 0.f};
    for (int base = s0; base < s1; base += 64) {
        const int cnt = min(64, s1 - base);
        const int nid = csr[base + min(lane, cnt - 1)];
        int j = 0;
        for (; j + 16 <= cnt; j += 16) {  // 16 edges: 4 loads in flight
            int sj[4];
#pragma unroll
            for (int k = 0; k < 4; ++k) sj[k] = __shfl(nid, j + 4 * k + q, 64);
            uint2 v[4];
#pragma unroll
            for (int k = 0; k < 4; ++k)
                v[k] = *(const uint2*)&z[(size_t)sj[k] * 128 + fl * 4];
#pragma unroll
            for (int k = 0; k < 4; ++k) {
                a0 += (f32x2){__uint_as_float(v[k].x << 16), __uint_as_float(v[k].x & 0xffff0000u)};
                a1 += (f32x2){__uint_as_float(v[k].y << 16), __uint_as_float(v[k].y & 0xffff0000u)};
            }
        }
        for (; j < cnt; j += 4) {  // tail: 4-edge round, predicated
            int idx = j + q;
            int sj = __shfl(nid, min(idx, cnt - 1), 64);
            uint2 v = *(const uint2*)&z[(size_t)sj * 128 + fl * 4];
            if (idx < cnt) {
                a0 += (f32x2){__uint_as_float(v.x << 16), __uint_as_float(v.x & 0xffff0000u)};
                a1 += (f32x2){__uint_as_float(v.y << 16), __uint_as_float(v.y & 0xffff0000u)};
            }
        }
    }
#pragma unroll
    for (int d = 16; d <= 32; d <<= 1) {
        a0.x += __shfl_xor(a0.x, d, 64);
        a0.y += __shfl_xor(a0.y, d, 64);
        a1.x += __shfl_xor(a1.x, d, 64);
        a1.y += __shfl_xor(a1.y, d, 64);
    }
    if (q == 0) {
        float r = rdeg[node];
        uint2 vr = *(const uint2*)&z[(size_t)node * 128 + 64 + fl * 4];
        float4 o;
        o.x = a0.x * r + __uint_as_float(vr.x << 16);
        o.y = a0.y * r + __uint_as_float(vr.x & 0xffff0000u);
        o.z = a1.x * r + __uint_as_float(vr.y << 16);
        o.w = a1.y * r + __uint_as_float(vr.y & 0xffff0000u);
        *(float4*)&out[(size_t)node * 64 + fl * 4] = o;
    }
}

// ------- MFMA GEMM (layers 0/1): out = [mean|h] @ Wcat^T + b, relu, bf16 out ---
// Staging via global_load_lds (linear LDS, pre-swizzled per-lane source).
// MFMA operands SWAPPED so each lane holds 4 consecutive feature cols of a node.

template <int FOUT, bool RELU>
__global__ __launch_bounds__(256) void gemm_kernel(
        const unsigned short* __restrict__ Abuf,   // mean [N][128] bf16
        const unsigned short* __restrict__ Hbuf,   // root [N][128] bf16
        const unsigned short* __restrict__ Wcat,   // [FOUT][256] bf16
        const float* __restrict__ bias,            // [FOUT] fp32
        unsigned short* __restrict__ outb,
        int N) {
    __shared__ unsigned short As[128 * 256];
    __shared__ unsigned short Ws[FOUT * 256];

    const int tid = threadIdx.x, wid = tid >> 6, lane = tid & 63;
    const int m0 = blockIdx.x * 128;
    char* Ac = (char*)As;
    char* Wc = (char*)Ws;
    const char* Ab = (const char*)Abuf;
    const char* Hb = (const char*)Hbuf;
    const char* Wb = (const char*)Wcat;

    // A tile: 128 rows x 512B (mean | root), swizzle applied via source address.
#pragma unroll
    for (int i = 0; i < 16; ++i) {
        int off = wid * 16384 + i * 1024 + lane * 16;
        int row = off >> 9, c = off & 511;
        int c2 = c ^ ((row & 7) << 4);
        const char* srcp = (c2 < 256) ? (Ab + (size_t)(m0 + row) * 256 + c2)
                                      : (Hb + (size_t)(m0 + row) * 256 + (c2 - 256));
        gld_lds16(srcp, Ac + wid * 16384 + i * 1024);
    }
    // W tile: FOUT rows x 512B.
#pragma unroll
    for (int i = 0; i < FOUT / 8; ++i) {
        int off = wid * (FOUT * 128) + i * 1024 + lane * 16;
        int row = off >> 9, c = off & 511;
        int c2 = c ^ ((row & 7) << 4);
        gld_lds16(Wb + (size_t)row * 512 + c2, Wc + wid * (FOUT * 128) + i * 1024);
    }
    asm volatile("s_waitcnt vmcnt(0)" ::: "memory");
    __syncthreads();

    constexpr int MI = (FOUT == 128) ? 4 : 2;
    constexpr int NI = 4;
    const int lm = lane & 15, ko = lane >> 4;
    const int wmBase = (FOUT == 128) ? (wid >> 1) * 64 : wid * 32;
    const int wnBase = (FOUT == 128) ? (wid & 1) * 64 : 0;

    f32x4 acc[MI][NI];
#pragma unroll
    for (int i = 0; i < MI; ++i)
#pragma unroll
        for (int j = 0; j < NI; ++j)
            acc[i][j] = (f32x4){0.f, 0.f, 0.f, 0.f};

#pragma unroll
    for (int ks = 0; ks < 8; ++ks) {
        const int kb = ks * 64 + ko * 16;
        bf16x8 a[MI], b[NI];
#pragma unroll
        for (int i = 0; i < MI; ++i) {
            int row = wmBase + i * 16 + lm;
            a[i] = *(const bf16x8*)(Ac + row * 512 + (kb ^ ((row & 7) << 4)));
        }
#pragma unroll
        for (int j = 0; j < NI; ++j) {
            int row = wnBase + j * 16 + lm;
            b[j] = *(const bf16x8*)(Wc + row * 512 + (kb ^ ((row & 7) << 4)));
        }
#pragma unroll
        for (int i = 0; i < MI; ++i)
#pragma unroll
            for (int j = 0; j < NI; ++j)
                acc[i][j] = __builtin_amdgcn_mfma_f32_16x16x32_bf16(b[j], a[i], acc[i][j], 0, 0, 0);
    }

    // lane holds: node = m0+wmBase+i*16+lm ; feature cols wnBase+j*16+ko*4 .. +3
#pragma unroll
    for (int i = 0; i < MI; ++i) {
        const int node = m0 + wmBase + i * 16 + lm;
        if (node < N) {
#pragma unroll
            for (int j = 0; j < NI; ++j) {
                const int col0 = wnBase + j * 16 + ko * 4;
                const float4 bv = *(const float4*)&bias[col0];
                float v0 = acc[i][j][0] + bv.x;
                float v1 = acc[i][j][1] + bv.y;
                float v2 = acc[i][j][2] + bv.z;
                float v3 = acc[i][j][3] + bv.w;
                if (RELU) {
                    v0 = fmaxf(v0, 0.f); v1 = fmaxf(v1, 0.f);
                    v2 = fmaxf(v2, 0.f); v3 = fmaxf(v3, 0.f);
                }
                uint2 o;
                o.x = (unsigned int)f2b(v0) | ((unsigned int)f2b(v1) << 16);
                o.y = (unsigned int)f2b(v2) | ((unsigned int)f2b(v3) << 16);
                *(uint2*)&outb[(size_t)node * FOUT + col0] = o;
            }
        }
    }
}

// ---------- MFMA GEMM (layer 2): z = h @ Wst^T + bst  (K=128, bf16 out) -------

__global__ __launch_bounds__(256) void gemmz_kernel(
        const unsigned short* __restrict__ A,    // [N][128] bf16
        const unsigned short* __restrict__ W,    // [128][128] bf16
        const float* __restrict__ bias,          // [128] fp32
        unsigned short* __restrict__ outb,       // [N][128] bf16
        int N) {
    __shared__ unsigned short As[128 * 128];
    __shared__ unsigned short Ws[128 * 128];

    const int tid = threadIdx.x, wid = tid >> 6, lane = tid & 63;
    const int m0 = blockIdx.x * 128;
    char* Ac = (char*)As;
    char* Wc = (char*)Ws;
    const char* Ab = (const char*)A;
    const char* Wb = (const char*)W;

#pragma unroll
    for (int i = 0; i < 8; ++i) {
        int off = wid * 8192 + i * 1024 + lane * 16;
        int row = off >> 8, c = off & 255;
        int c2 = c ^ ((row & 7) << 4);
        gld_lds16(Ab + (size_t)(m0 + row) * 256 + c2, Ac + wid * 8192 + i * 1024);
    }
#pragma unroll
    for (int i = 0; i < 8; ++i) {
        int off = wid * 8192 + i * 1024 + lane * 16;
        int row = off >> 8, c = off & 255;
        int c2 = c ^ ((row & 7) << 4);
        gld_lds16(Wb + (size_t)row * 256 + c2, Wc + wid * 8192 + i * 1024);
    }
    asm volatile("s_waitcnt vmcnt(0)" ::: "memory");
    __syncthreads();

    const int lm = lane & 15, ko = lane >> 4;
    const int wmBase = (wid >> 1) * 64;
    const int wnBase = (wid & 1) * 64;

    f32x4 acc[4][4];
#pragma unroll
    for (int i = 0; i < 4; ++i)
#pragma unroll
        for (int j = 0; j < 4; ++j)
            acc[i][j] = (f32x4){0.f, 0.f, 0.f, 0.f};

#pragma unroll
    for (int ks = 0; ks < 4; ++ks) {
        const int kb = ks * 64 + ko * 16;
        bf16x8 a[4], b[4];
#pragma unroll
        for (int i = 0; i < 4; ++i) {
            int row = wmBase + i * 16 + lm;
            a[i] = *(const bf16x8*)(Ac + row * 256 + (kb ^ ((row & 7) << 4)));
        }
#pragma unroll
        for (int j = 0; j < 4; ++j) {
            int row = wnBase + j * 16 + lm;
            b[j] = *(const bf16x8*)(Wc + row * 256 + (kb ^ ((row & 7) << 4)));
        }
#pragma unroll
        for (int i = 0; i < 4; ++i)
#pragma unroll
            for (int j = 0; j < 4; ++j)
                acc[i][j] = __builtin_amdgcn_mfma_f32_16x16x32_bf16(b[j], a[i], acc[i][j], 0, 0, 0);
    }

#pragma unroll
    for (int i = 0; i < 4; ++i) {
        const int node = m0 + wmBase + i * 16 + lm;
        if (node < N) {
#pragma unroll
            for (int j = 0; j < 4; ++j) {
                const int col0 = wnBase + j * 16 + ko * 4;
                const float4 bv = *(const float4*)&bias[col0];
                uint2 o;
                o.x = (unsigned int)f2b(acc[i][j][0] + bv.x) |
                      ((unsigned int)f2b(acc[i][j][1] + bv.y) << 16);
                o.y = (unsigned int)f2b(acc[i][j][2] + bv.z) |
                      ((unsigned int)f2b(acc[i][j][3] + bv.w) << 16);
                *(uint2*)&outb[(size_t)node * 128 + col0] = o;
            }
        }
    }
}

// ---------------- launch ----------------

extern "C" void kernel_launch(void* const* d_in, const int* in_sizes, int n_in,
                              void* d_out, int out_size, void* d_ws, size_t ws_size,
                              hipStream_t stream) {
    const float* x   = (const float*)d_in[0];
    const int*   ei  = (const int*)d_in[1];
    const float* Wl0 = (const float*)d_in[2];
    const float* Wr0 = (const float*)d_in[3];
    const float* b0  = (const float*)d_in[4];
    const float* Wl1 = (const float*)d_in[5];
    const float* Wr1 = (const float*)d_in[6];
    const float* b1  = (const float*)d_in[7];
    const float* Wl2 = (const float*)d_in[8];
    const float* Wr2 = (const float*)d_in[9];
    const float* b2  = (const float*)d_in[10];
    float* out = (float*)d_out;

    const int N = in_sizes[0] / NF;
    const int E = in_sizes[1] / 2;
    const int* srcv = ei;
    const int* dstv = ei + E;

    const int NB   = (N + 255) >> 8;
    const int NBLK = (E + CHUNK - 1) / CHUNK;
    const int T    = NB * NBLK;
    const int NS   = (T + 255) / 256;

    char* w = (char*)d_ws;
    auto alloc = [&](size_t bytes) {
        void* p = (void*)w;
        w += (bytes + 255) & ~(size_t)255;
        return p;
    };
    unsigned short* xb   = (unsigned short*)alloc((size_t)N * NF * 2);
    unsigned short* h1b  = (unsigned short*)alloc((size_t)N * NF * 2);
    unsigned short* h2b  = (unsigned short*)alloc((size_t)N * NF * 2);
    unsigned short* mb   = (unsigned short*)alloc((size_t)N * NF * 2);
    unsigned short* z2b  = (unsigned short*)alloc((size_t)N * NF * 2);
    unsigned short* Wc0  = (unsigned short*)alloc((size_t)128 * 256 * 2);
    unsigned short* Wc1  = (unsigned short*)alloc((size_t)128 * 256 * 2);
    unsigned short* Wst2 = (unsigned short*)alloc((size_t)128 * 128 * 2);
    float*          bst2 = (float*)alloc((size_t)128 * 4);
    int*   offs   = (int*)alloc((size_t)(N + 1) * 4);
    int*   csr    = (int*)alloc((size_t)E * 4);
    float* rdeg   = (float*)alloc((size_t)N * 4);
    unsigned int* recs = (unsigned int*)alloc((size_t)E * 4);
    int*   hist   = (int*)alloc((size_t)T * 4);
    int*   base   = (int*)alloc((size_t)T * 4);
    int*   bstart = (int*)alloc((size_t)(NB + 1) * 4);
    int*   sb1    = (int*)alloc((size_t)1024 * 4);
    int*   sb2    = (int*)alloc((size_t)1024 * 4);

    const int n4 = N * NF / 4;
    cvt_kernel<<<(n4 + 255) / 256, 256, 0, stream>>>(x, xb, n4);
    wcat_kernel<<<(128 * 128 + 255) / 256, 256, 0, stream>>>(Wl0, Wr0, Wc0, 128 * 128);
    wcat_kernel<<<(128 * 128 + 255) / 256, 256, 0, stream>>>(Wl1, Wr1, Wc1, 128 * 128);
    wstack_kernel<<<(64 * 128 + 255) / 256, 256, 0, stream>>>(Wl2, Wr2, b2, Wst2, bst2, 64 * 128);

    hist_kernel<<<NBLK, 256, 0, stream>>>(dstv, hist, E, NB);
    sb_sum<<<NS, 256, 0, stream>>>(hist, sb1, T, NB, NBLK);
    sb_scan<<<1, 1024, 0, stream>>>(sb1, sb2, NS);
    sb_apply<<<NS, 256, 0, stream>>>(hist, sb2, base, T, NB, NBLK);
    bstart_kernel<<<1, 512, 0, stream>>>(base, bstart, NB, NBLK, E);
    scat_kernel<<<NBLK, 256, 0, stream>>>(srcv, dstv, base, recs, E, NB, NBLK);
    csr_kernel<<<NB, 256, 0, stream>>>(recs, bstart, offs, rdeg, csr, N, E);

    const int ab = (N + 3) / 4;
    const int gb = (N + 127) / 128;

    agg_kernel<<<ab, 256, 0, stream>>>(xb, offs, csr, rdeg, mb, N);
    gemm_kernel<128, true><<<gb, 256, 0, stream>>>(mb, xb, Wc0, b0, h1b, N);

    agg_kernel<<<ab, 256, 0, stream>>>(h1b, offs, csr, rdeg, mb, N);
    gemm_kernel<128, true><<<gb, 256, 0, stream>>>(mb, h1b, Wc1, b1, h2b, N);

    gemmz_kernel<<<gb, 256, 0, stream>>>(h2b, Wst2, bst2, z2b, N);
    agg2_kernel<<<ab, 256, 0, stream>>>(z2b, offs, csr, rdeg, out, N);
}

// Round 7
// 298.577 us; speedup vs baseline: 5.8222x; 1.0435x over previous
//
#include <hip/hip_runtime.h>

#define NF 128      // feature width for x / hidden layers
#define CHUNK 4096  // edges per block in CSR-build phase 1

typedef __attribute__((ext_vector_type(8))) short bf16x8;
typedef __attribute__((ext_vector_type(4))) float f32x4;
typedef __attribute__((ext_vector_type(2))) float f32x2;

__device__ __forceinline__ unsigned short f2b(float f) {
    unsigned int u = __float_as_uint(f);
    unsigned int r = (u + 0x7fffu + ((u >> 16) & 1u)) >> 16;  // round-nearest-even
    return (unsigned short)r;
}

// async global->LDS, 16B per lane. LDS dest = wave-uniform base (+lane*16 by HW);
// global src is per-lane.
__device__ __forceinline__ void gld_lds16(const void* g, const void* l) {
    __builtin_amdgcn_global_load_lds(
        (const __attribute__((address_space(1))) unsigned int*)(unsigned long long)g,
        (__attribute__((address_space(3))) unsigned int*)(unsigned int)(unsigned long long)l,
        16, 0, 0);
}

// ================= CSR build: bucketed two-phase counting sort =================

__global__ __launch_bounds__(256) void hist_kernel(const int* __restrict__ dst,
                                                   int* __restrict__ hist,
                                                   int E, int NB) {
    __shared__ int h[512];
    const int blk = blockIdx.x;
    for (int i = threadIdx.x; i < NB; i += 256) h[i] = 0;
    __syncthreads();
    const int e0 = blk * CHUNK;
    for (int i = threadIdx.x; i < CHUNK; i += 256) {
        int e = e0 + i;
        if (e < E) atomicAdd(&h[dst[e] >> 8], 1);
    }
    __syncthreads();
    for (int i = threadIdx.x; i < NB; i += 256) hist[blk * NB + i] = h[i];
}

__global__ __launch_bounds__(256) void sb_sum(const int* __restrict__ hist,
                                              int* __restrict__ bsum,
                                              int T, int NB, int NBLK) {
    int i = blockIdx.x * 256 + threadIdx.x;
    int v = 0;
    if (i < T) {
        int b = i / NBLK, blk = i - b * NBLK;
        v = hist[blk * NB + b];
    }
#pragma unroll
    for (int d = 32; d; d >>= 1) v += __shfl_down(v, d, 64);
    __shared__ int wsum[4];
    if ((threadIdx.x & 63) == 0) wsum[threadIdx.x >> 6] = v;
    __syncthreads();
    if (threadIdx.x == 0) bsum[blockIdx.x] = wsum[0] + wsum[1] + wsum[2] + wsum[3];
}

__global__ __launch_bounds__(1024) void sb_scan(const int* __restrict__ bsum,
                                                int* __restrict__ bpre, int NS) {
    __shared__ int s[1024];
    int t = threadIdx.x;
    int v = (t < NS) ? bsum[t] : 0;
    s[t] = v;
    __syncthreads();
    for (int d = 1; d < 1024; d <<= 1) {
        int u = (t >= d) ? s[t - d] : 0;
        __syncthreads();
        s[t] += u;
        __syncthreads();
    }
    if (t < NS) bpre[t] = s[t] - v;
}

__global__ __launch_bounds__(256) void sb_apply(const int* __restrict__ hist,
                                                const int* __restrict__ bpre,
                                                int* __restrict__ base,
                                                int T, int NB, int NBLK) {
    __shared__ int s[256];
    int i = blockIdx.x * 256 + threadIdx.x;
    int t = threadIdx.x;
    int v = 0;
    if (i < T) {
        int b = i / NBLK, blk = i - b * NBLK;
        v = hist[blk * NB + b];
    }
    s[t] = v;
    __syncthreads();
    for (int d = 1; d < 256; d <<= 1) {
        int u = (t >= d) ? s[t - d] : 0;
        __syncthreads();
        s[t] += u;
        __syncthreads();
    }
    if (i < T) base[i] = bpre[blockIdx.x] + s[t] - v;
}

__global__ __launch_bounds__(512) void bstart_kernel(const int* __restrict__ base,
                                                     int* __restrict__ bstart,
                                                     int NB, int NBLK, int E) {
    int i = threadIdx.x;
    if (i < NB) bstart[i] = base[i * NBLK];
    if (i == NB) bstart[i] = E;
}

__global__ __launch_bounds__(256) void scat_kernel(const int* __restrict__ src,
                                                   const int* __restrict__ dst,
                                                   const int* __restrict__ base,
                                                   unsigned int* __restrict__ recs,
                                                   int E, int NB, int NBLK) {
    __shared__ int cur[512];
    const int blk = blockIdx.x;
    for (int b = threadIdx.x; b < NB; b += 256) cur[b] = base[b * NBLK + blk];
    __syncthreads();
    const int e0 = blk * CHUNK;
    for (int i = threadIdx.x; i < CHUNK; i += 256) {
        int e = e0 + i;
        if (e >= E) continue;
        int d = dst[e];
        int b = d >> 8;
        int pos = atomicAdd(&cur[b], 1);
        recs[pos] = (unsigned int)src[e] | ((unsigned int)(d & 255) << 24);
    }
}

__global__ __launch_bounds__(256) void csr_kernel(const unsigned int* __restrict__ recs,
                                                  const int* __restrict__ bstart,
                                                  int* __restrict__ offs,
                                                  float* __restrict__ rdeg,
                                                  int* __restrict__ csr,
                                                  int N, int E) {
    __shared__ int cnt[256];
    __shared__ int sc[256];
    __shared__ int cur[256];
    const int b = blockIdx.x;
    const int t = threadIdx.x;
    const int s0 = bstart[b], s1 = bstart[b + 1];
    cnt[t] = 0;
    __syncthreads();
    for (int i = s0 + t; i < s1; i += 256) atomicAdd(&cnt[recs[i] >> 24], 1);
    __syncthreads();
    int v = cnt[t];
    sc[t] = v;
    __syncthreads();
    for (int d = 1; d < 256; d <<= 1) {
        int u = (t >= d) ? sc[t - d] : 0;
        __syncthreads();
        sc[t] += u;
        __syncthreads();
    }
    int excl = sc[t] - v;
    int node = b * 256 + t;
    if (node < N) {
        offs[node] = s0 + excl;
        rdeg[node] = 1.0f / (float)(v > 1 ? v : 1);
        if (node == N - 1) offs[N] = E;
    }
    cur[t] = s0 + excl;
    __syncthreads();
    for (int i = s0 + t; i < s1; i += 256) {
        unsigned int r = recs[i];
        int pos = atomicAdd(&cur[r >> 24], 1);
        csr[pos] = (int)(r & 0xFFFFFFu);
    }
}

// ---------------- fp32 -> bf16 conversions ----------------

__global__ void cvt_kernel(const float* __restrict__ x, unsigned short* __restrict__ xb, int n4) {
    int i = blockIdx.x * 256 + threadIdx.x;
    if (i >= n4) return;
    float4 v = *(const float4*)&x[(size_t)i * 4];
    uint2 o;
    o.x = (unsigned int)f2b(v.x) | ((unsigned int)f2b(v.y) << 16);
    o.y = (unsigned int)f2b(v.z) | ((unsigned int)f2b(v.w) << 16);
    *(uint2*)&xb[(size_t)i * 4] = o;
}

__global__ void wcat_kernel(const float* __restrict__ Wl, const float* __restrict__ Wr,
                            unsigned short* __restrict__ Wc, int total /*128*128*/) {
    int i = blockIdx.x * 256 + threadIdx.x;
    if (i >= total) return;
    int f = i >> 7, k = i & 127;
    Wc[f * 256 + k] = f2b(Wl[i]);
    Wc[f * 256 + 128 + k] = f2b(Wr[i]);
}

__global__ void wstack_kernel(const float* __restrict__ Wl, const float* __restrict__ Wr,
                              const float* __restrict__ b2,
                              unsigned short* __restrict__ Wst, float* __restrict__ bst,
                              int total /*64*128*/) {
    int i = blockIdx.x * 256 + threadIdx.x;
    if (i >= total) return;
    int f = i >> 7, k = i & 127;
    Wst[f * 128 + k] = f2b(Wl[i]);
    Wst[(f + 64) * 128 + k] = f2b(Wr[i]);
    if (k == 0) {
        bst[f] = 0.f;
        bst[f + 64] = b2[f];
    }
}

// -------- mean aggregation (bf16 in/out): one node/wave, full-row loads -------
// Each load: 64 lanes x 4B = one 256B row (clean coalescing). 16 loads in flight.
// Tail: single clamped group (dup loads are L1 hits), predicated accumulates.

__global__ __launch_bounds__(256) void agg_kernel(
        const unsigned short* __restrict__ h, const int* __restrict__ offs,
        const int* __restrict__ csr, const float* __restrict__ rdeg,
        unsigned short* __restrict__ meanout, int N) {
    const int node = blockIdx.x * 4 + (threadIdx.x >> 6);
    const int lane = threadIdx.x & 63;
    if (node >= N) return;
    const int s0 = offs[node], s1 = offs[node + 1];
    const char* hb = (const char*)h;
    f32x2 acc = {0.f, 0.f};
    for (int base = s0; base < s1; base += 64) {
        const int cnt = min(64, s1 - base);
        const int boff = csr[base + min(lane, cnt - 1)] << 8;  // row byte offset
        for (int j = 0; j < cnt; j += 16) {
            if (j + 16 <= cnt) {
                int o[16];
#pragma unroll
                for (int k = 0; k < 16; ++k) o[k] = __shfl(boff, j + k, 64);
                unsigned int v[16];
#pragma unroll
                for (int k = 0; k < 16; ++k)
                    v[k] = *(const unsigned int*)(hb + o[k] + lane * 4);
#pragma unroll
                for (int k = 0; k < 16; ++k)
                    acc += (f32x2){__uint_as_float(v[k] << 16),
                                   __uint_as_float(v[k] & 0xffff0000u)};
            } else {
                int o[16];
#pragma unroll
                for (int k = 0; k < 16; ++k) o[k] = __shfl(boff, min(j + k, cnt - 1), 64);
                unsigned int v[16];
#pragma unroll
                for (int k = 0; k < 16; ++k)
                    v[k] = *(const unsigned int*)(hb + o[k] + lane * 4);
#pragma unroll
                for (int k = 0; k < 16; ++k)
                    if (j + k < cnt)
                        acc += (f32x2){__uint_as_float(v[k] << 16),
                                       __uint_as_float(v[k] & 0xffff0000u)};
            }
        }
    }
    float r = rdeg[node];
    unsigned int o = (unsigned int)f2b(acc.x * r) | ((unsigned int)f2b(acc.y * r) << 16);
    *(unsigned int*)&meanout[(size_t)node * NF + lane * 2] = o;
}

// ---- layer-2 final agg: out[i] = mean_j zl[j] + zr[i]; one node/wave ---------
// zl row = 128B = 32 lanes x 4B; halves process alternate edges (16 in flight).

__global__ __launch_bounds__(256) void agg2_kernel(
        const unsigned short* __restrict__ z, const int* __restrict__ offs,
        const int* __restrict__ csr, const float* __restrict__ rdeg,
        float* __restrict__ out, int N) {
    const int node = blockIdx.x * 4 + (threadIdx.x >> 6);
    const int lane = threadIdx.x & 63;
    if (node >= N) return;
    const int hlf = lane >> 5;   // which edge of a pair
    const int fl  = lane & 31;   // uint at byte fl*4 of zl row
    const int s0 = offs[node], s1 = offs[node + 1];
    const char* zb = (const char*)z;
    f32x2 acc = {0.f, 0.f};
    for (int base = s0; base < s1; base += 64) {
        const int cnt = min(64, s1 - base);
        const int boff = csr[base + min(lane, cnt - 1)] << 8;  // z row byte offset
        for (int j = 0; j < cnt; j += 16) {
            if (j + 16 <= cnt) {
                int o[8];
#pragma unroll
                for (int k = 0; k < 8; ++k) o[k] = __shfl(boff, j + 2 * k + hlf, 64);
                unsigned int v[8];
#pragma unroll
                for (int k = 0; k < 8; ++k)
                    v[k] = *(const unsigned int*)(zb + o[k] + fl * 4);
#pragma unroll
                for (int k = 0; k < 8; ++k)
                    acc += (f32x2){__uint_as_float(v[k] << 16),
                                   __uint_as_float(v[k] & 0xffff0000u)};
            } else {
                int o[8];
#pragma unroll
                for (int k = 0; k < 8; ++k)
                    o[k] = __shfl(boff, min(j + 2 * k + hlf, cnt - 1), 64);
                unsigned int v[8];
#pragma unroll
                for (int k = 0; k < 8; ++k)
                    v[k] = *(const unsigned int*)(zb + o[k] + fl * 4);
#pragma unroll
                for (int k = 0; k < 8; ++k)
                    if (j + 2 * k + hlf < cnt)
                        acc += (f32x2){__uint_as_float(v[k] << 16),
                                       __uint_as_float(v[k] & 0xffff0000u)};
            }
        }
    }
    acc.x += __shfl_xor(acc.x, 32, 64);
    acc.y += __shfl_xor(acc.y, 32, 64);
    if (hlf == 0) {
        float r = rdeg[node];
        unsigned int vr = *(const unsigned int*)(zb + (size_t)node * 256 + 128 + fl * 4);
        float2 o;
        o.x = acc.x * r + __uint_as_float(vr << 16);
        o.y = acc.y * r + __uint_as_float(vr & 0xffff0000u);
        *(float2*)&out[(size_t)node * 64 + fl * 2] = o;
    }
}

// ------- MFMA GEMM (layers 0/1): out = [mean|h] @ Wcat^T + b, relu, bf16 out ---

template <int FOUT, bool RELU>
__global__ __launch_bounds__(256) void gemm_kernel(
        const unsigned short* __restrict__ Abuf,   // mean [N][128] bf16
        const unsigned short* __restrict__ Hbuf,   // root [N][128] bf16
        const unsigned short* __restrict__ Wcat,   // [FOUT][256] bf16
        const float* __restrict__ bias,            // [FOUT] fp32
        unsigned short* __restrict__ outb,
        int N) {
    __shared__ unsigned short As[128 * 256];
    __shared__ unsigned short Ws[FOUT * 256];

    const int tid = threadIdx.x, wid = tid >> 6, lane = tid & 63;
    const int m0 = blockIdx.x * 128;
    char* Ac = (char*)As;
    char* Wc = (char*)Ws;
    const char* Ab = (const char*)Abuf;
    const char* Hb = (const char*)Hbuf;
    const char* Wb = (const char*)Wcat;

#pragma unroll
    for (int i = 0; i < 16; ++i) {
        int off = wid * 16384 + i * 1024 + lane * 16;
        int row = off >> 9, c = off & 511;
        int c2 = c ^ ((row & 7) << 4);
        const char* srcp = (c2 < 256) ? (Ab + (size_t)(m0 + row) * 256 + c2)
                                      : (Hb + (size_t)(m0 + row) * 256 + (c2 - 256));
        gld_lds16(srcp, Ac + wid * 16384 + i * 1024);
    }
#pragma unroll
    for (int i = 0; i < FOUT / 8; ++i) {
        int off = wid * (FOUT * 128) + i * 1024 + lane * 16;
        int row = off >> 9, c = off & 511;
        int c2 = c ^ ((row & 7) << 4);
        gld_lds16(Wb + (size_t)row * 512 + c2, Wc + wid * (FOUT * 128) + i * 1024);
    }
    asm volatile("s_waitcnt vmcnt(0)" ::: "memory");
    __syncthreads();

    constexpr int MI = (FOUT == 128) ? 4 : 2;
    constexpr int NI = 4;
    const int lm = lane & 15, ko = lane >> 4;
    const int wmBase = (FOUT == 128) ? (wid >> 1) * 64 : wid * 32;
    const int wnBase = (FOUT == 128) ? (wid & 1) * 64 : 0;

    f32x4 acc[MI][NI];
#pragma unroll
    for (int i = 0; i < MI; ++i)
#pragma unroll
        for (int j = 0; j < NI; ++j)
            acc[i][j] = (f32x4){0.f, 0.f, 0.f, 0.f};

#pragma unroll
    for (int ks = 0; ks < 8; ++ks) {
        const int kb = ks * 64 + ko * 16;
        bf16x8 a[MI], b[NI];
#pragma unroll
        for (int i = 0; i < MI; ++i) {
            int row = wmBase + i * 16 + lm;
            a[i] = *(const bf16x8*)(Ac + row * 512 + (kb ^ ((row & 7) << 4)));
        }
#pragma unroll
        for (int j = 0; j < NI; ++j) {
            int row = wnBase + j * 16 + lm;
            b[j] = *(const bf16x8*)(Wc + row * 512 + (kb ^ ((row & 7) << 4)));
        }
#pragma unroll
        for (int i = 0; i < MI; ++i)
#pragma unroll
            for (int j = 0; j < NI; ++j)
                acc[i][j] = __builtin_amdgcn_mfma_f32_16x16x32_bf16(b[j], a[i], acc[i][j], 0, 0, 0);
    }

#pragma unroll
    for (int i = 0; i < MI; ++i) {
        const int node = m0 + wmBase + i * 16 + lm;
        if (node < N) {
#pragma unroll
            for (int j = 0; j < NI; ++j) {
                const int col0 = wnBase + j * 16 + ko * 4;
                const float4 bv = *(const float4*)&bias[col0];
                float v0 = acc[i][j][0] + bv.x;
                float v1 = acc[i][j][1] + bv.y;
                float v2 = acc[i][j][2] + bv.z;
                float v3 = acc[i][j][3] + bv.w;
                if (RELU) {
                    v0 = fmaxf(v0, 0.f); v1 = fmaxf(v1, 0.f);
                    v2 = fmaxf(v2, 0.f); v3 = fmaxf(v3, 0.f);
                }
                uint2 o;
                o.x = (unsigned int)f2b(v0) | ((unsigned int)f2b(v1) << 16);
                o.y = (unsigned int)f2b(v2) | ((unsigned int)f2b(v3) << 16);
                *(uint2*)&outb[(size_t)node * FOUT + col0] = o;
            }
        }
    }
}

// ---------- MFMA GEMM (layer 2): z = h @ Wst^T + bst  (K=128, bf16 out) -------

__global__ __launch_bounds__(256) void gemmz_kernel(
        const unsigned short* __restrict__ A,    // [N][128] bf16
        const unsigned short* __restrict__ W,    // [128][128] bf16
        const float* __restrict__ bias,          // [128] fp32
        unsigned short* __restrict__ outb,       // [N][128] bf16
        int N) {
    __shared__ unsigned short As[128 * 128];
    __shared__ unsigned short Ws[128 * 128];

    const int tid = threadIdx.x, wid = tid >> 6, lane = tid & 63;
    const int m0 = blockIdx.x * 128;
    char* Ac = (char*)As;
    char* Wc = (char*)Ws;
    const char* Ab = (const char*)A;
    const char* Wb = (const char*)W;

#pragma unroll
    for (int i = 0; i < 8; ++i) {
        int off = wid * 8192 + i * 1024 + lane * 16;
        int row = off >> 8, c = off & 255;
        int c2 = c ^ ((row & 7) << 4);
        gld_lds16(Ab + (size_t)(m0 + row) * 256 + c2, Ac + wid * 8192 + i * 1024);
    }
#pragma unroll
    for (int i = 0; i < 8; ++i) {
        int off = wid * 8192 + i * 1024 + lane * 16;
        int row = off >> 8, c = off & 255;
        int c2 = c ^ ((row & 7) << 4);
        gld_lds16(Wb + (size_t)row * 256 + c2, Wc + wid * 8192 + i * 1024);
    }
    asm volatile("s_waitcnt vmcnt(0)" ::: "memory");
    __syncthreads();

    const int lm = lane & 15, ko = lane >> 4;
    const int wmBase = (wid >> 1) * 64;
    const int wnBase = (wid & 1) * 64;

    f32x4 acc[4][4];
#pragma unroll
    for (int i = 0; i < 4; ++i)
#pragma unroll
        for (int j = 0; j < 4; ++j)
            acc[i][j] = (f32x4){0.f, 0.f, 0.f, 0.f};

#pragma unroll
    for (int ks = 0; ks < 4; ++ks) {
        const int kb = ks * 64 + ko * 16;
        bf16x8 a[4], b[4];
#pragma unroll
        for (int i = 0; i < 4; ++i) {
            int row = wmBase + i * 16 + lm;
            a[i] = *(const bf16x8*)(Ac + row * 256 + (kb ^ ((row & 7) << 4)));
        }
#pragma unroll
        for (int j = 0; j < 4; ++j) {
            int row = wnBase + j * 16 + lm;
            b[j] = *(const bf16x8*)(Wc + row * 256 + (kb ^ ((row & 7) << 4)));
        }
#pragma unroll
        for (int i = 0; i < 4; ++i)
#pragma unroll
            for (int j = 0; j < 4; ++j)
                acc[i][j] = __builtin_amdgcn_mfma_f32_16x16x32_bf16(b[j], a[i], acc[i][j], 0, 0, 0);
    }

#pragma unroll
    for (int i = 0; i < 4; ++i) {
        const int node = m0 + wmBase + i * 16 + lm;
        if (node < N) {
#pragma unroll
            for (int j = 0; j < 4; ++j) {
                const int col0 = wnBase + j * 16 + ko * 4;
                const float4 bv = *(const float4*)&bias[col0];
                uint2 o;
                o.x = (unsigned int)f2b(acc[i][j][0] + bv.x) |
                      ((unsigned int)f2b(acc[i][j][1] + bv.y) << 16);
                o.y = (unsigned int)f2b(acc[i][j][2] + bv.z) |
                      ((unsigned int)f2b(acc[i][j][3] + bv.w) << 16);
                *(uint2*)&outb[(size_t)node * 128 + col0] = o;
            }
        }
    }
}

// ---------------- launch ----------------

extern "C" void kernel_launch(void* const* d_in, const int* in_sizes, int n_in,
                              void* d_out, int out_size, void* d_ws, size_t ws_size,
                              hipStream_t stream) {
    const float* x   = (const float*)d_in[0];
    const int*   ei  = (const int*)d_in[1];
    const float* Wl0 = (const float*)d_in[2];
    const float* Wr0 = (const float*)d_in[3];
    const float* b0  = (const float*)d_in[4];
    const float* Wl1 = (const float*)d_in[5];
    const float* Wr1 = (const float*)d_in[6];
    const float* b1  = (const float*)d_in[7];
    const float* Wl2 = (const float*)d_in[8];
    const float* Wr2 = (const float*)d_in[9];
    const float* b2  = (const float*)d_in[10];
    float* out = (float*)d_out;

    const int N = in_sizes[0] / NF;
    const int E = in_sizes[1] / 2;
    const int* srcv = ei;
    const int* dstv = ei + E;

    const int NB   = (N + 255) >> 8;
    const int NBLK = (E + CHUNK - 1) / CHUNK;
    const int T    = NB * NBLK;
    const int NS   = (T + 255) / 256;

    char* w = (char*)d_ws;
    auto alloc = [&](size_t bytes) {
        void* p = (void*)w;
        w += (bytes + 255) & ~(size_t)255;
        return p;
    };
    unsigned short* xb   = (unsigned short*)alloc((size_t)N * NF * 2);
    unsigned short* h1b  = (unsigned short*)alloc((size_t)N * NF * 2);
    unsigned short* h2b  = (unsigned short*)alloc((size_t)N * NF * 2);
    unsigned short* mb   = (unsigned short*)alloc((size_t)N * NF * 2);
    unsigned short* z2b  = (unsigned short*)alloc((size_t)N * NF * 2);
    unsigned short* Wc0  = (unsigned short*)alloc((size_t)128 * 256 * 2);
    unsigned short* Wc1  = (unsigned short*)alloc((size_t)128 * 256 * 2);
    unsigned short* Wst2 = (unsigned short*)alloc((size_t)128 * 128 * 2);
    float*          bst2 = (float*)alloc((size_t)128 * 4);
    int*   offs   = (int*)alloc((size_t)(N + 1) * 4);
    int*   csr    = (int*)alloc((size_t)E * 4);
    float* rdeg   = (float*)alloc((size_t)N * 4);
    unsigned int* recs = (unsigned int*)alloc((size_t)E * 4);
    int*   hist   = (int*)alloc((size_t)T * 4);
    int*   base   = (int*)alloc((size_t)T * 4);
    int*   bstart = (int*)alloc((size_t)(NB + 1) * 4);
    int*   sb1    = (int*)alloc((size_t)1024 * 4);
    int*   sb2    = (int*)alloc((size_t)1024 * 4);

    const int n4 = N * NF / 4;
    cvt_kernel<<<(n4 + 255) / 256, 256, 0, stream>>>(x, xb, n4);
    wcat_kernel<<<(128 * 128 + 255) / 256, 256, 0, stream>>>(Wl0, Wr0, Wc0, 128 * 128);
    wcat_kernel<<<(128 * 128 + 255) / 256, 256, 0, stream>>>(Wl1, Wr1, Wc1, 128 * 128);
    wstack_kernel<<<(64 * 128 + 255) / 256, 256, 0, stream>>>(Wl2, Wr2, b2, Wst2, bst2, 64 * 128);

    hist_kernel<<<NBLK, 256, 0, stream>>>(dstv, hist, E, NB);
    sb_sum<<<NS, 256, 0, stream>>>(hist, sb1, T, NB, NBLK);
    sb_scan<<<1, 1024, 0, stream>>>(sb1, sb2, NS);
    sb_apply<<<NS, 256, 0, stream>>>(hist, sb2, base, T, NB, NBLK);
    bstart_kernel<<<1, 512, 0, stream>>>(base, bstart, NB, NBLK, E);
    scat_kernel<<<NBLK, 256, 0, stream>>>(srcv, dstv, base, recs, E, NB, NBLK);
    csr_kernel<<<NB, 256, 0, stream>>>(recs, bstart, offs, rdeg, csr, N, E);

    const int ab = (N + 3) / 4;
    const int gb = (N + 127) / 128;

    agg_kernel<<<ab, 256, 0, stream>>>(xb, offs, csr, rdeg, mb, N);
    gemm_kernel<128, true><<<gb, 256, 0, stream>>>(mb, xb, Wc0, b0, h1b, N);

    agg_kernel<<<ab, 256, 0, stream>>>(h1b, offs, csr, rdeg, mb, N);
    gemm_kernel<128, true><<<gb, 256, 0, stream>>>(mb, h1b, Wc1, b1, h2b, N);

    gemmz_kernel<<<gb, 256, 0, stream>>>(h2b, Wst2, bst2, z2b, N);
    agg2_kernel<<<ab, 256, 0, stream>>>(z2b, offs, csr, rdeg, out, N);
}